// Round 4
// baseline (520.326 us; speedup 1.0000x reference)
//
#include <hip/hip_runtime.h>
#include <math.h>
#include <stdint.h>

#define BATCH 4
#define SEQ   1024
#define NXDIM 1024
#define NHEAD 16
#define DHEAD 64
#define QKVN  3072
#define MROWS 4096
#define KDIM  1024

typedef short short8 __attribute__((ext_vector_type(8)));   // 8 x bf16 bits
typedef float f32x4  __attribute__((ext_vector_type(4)));

typedef const __attribute__((address_space(1))) unsigned int* gptr_t;
typedef __attribute__((address_space(3))) unsigned int* lptr_t;

__device__ __forceinline__ unsigned short f2bf(float f) {
    unsigned int u = __float_as_uint(f);
    u += 0x7FFF + ((u >> 16) & 1);          // round-to-nearest-even
    return (unsigned short)(u >> 16);
}
__device__ __forceinline__ float bf2f(unsigned short h) {
    return __uint_as_float(((unsigned int)h) << 16);
}

// ---------------------------------------------------------------------------
// Split x (M=4096, K=1024, row-major) into hi/lo bf16 in A-tiled layout:
// [mt:32][kt:32][g:8][khalf:4][r16:16][k8:8]  (tile = 4096 elems = 8 KB)
// Thread t handles 8 consecutive k; tiled linear offset == t*8 by construction.
// ---------------------------------------------------------------------------
__global__ __launch_bounds__(256) void split_x_kernel(
    const float* __restrict__ x, unsigned short* __restrict__ xh,
    unsigned short* __restrict__ xl)
{
    const int t = blockIdx.x * 256 + threadIdx.x;       // 524288 threads
    const int tile = t >> 9, u = t & 511;
    const int mt = tile >> 5, kt = tile & 31;
    const int g = u >> 6, khalf = (u >> 4) & 3, r16 = u & 15;
    const int m = mt * 128 + g * 16 + r16;
    const int k = kt * 32 + khalf * 8;
    const float4 v0 = *(const float4*)&x[(size_t)m * KDIM + k];
    const float4 v1 = *(const float4*)&x[(size_t)m * KDIM + k + 4];
    const float vv[8] = {v0.x, v0.y, v0.z, v0.w, v1.x, v1.y, v1.z, v1.w};
    unsigned short h[8], l[8];
    #pragma unroll
    for (int e = 0; e < 8; ++e) {
        h[e] = f2bf(vv[e]);
        l[e] = f2bf(vv[e] - bf2f(h[e]));
    }
    uint4 ph, pl;
    ph.x = (unsigned)h[0] | ((unsigned)h[1] << 16);
    ph.y = (unsigned)h[2] | ((unsigned)h[3] << 16);
    ph.z = (unsigned)h[4] | ((unsigned)h[5] << 16);
    ph.w = (unsigned)h[6] | ((unsigned)h[7] << 16);
    pl.x = (unsigned)l[0] | ((unsigned)l[1] << 16);
    pl.y = (unsigned)l[2] | ((unsigned)l[3] << 16);
    pl.z = (unsigned)l[4] | ((unsigned)l[5] << 16);
    pl.w = (unsigned)l[6] | ((unsigned)l[7] << 16);
    *(uint4*)&xh[(size_t)t * 8] = ph;
    *(uint4*)&xl[(size_t)t * 8] = pl;
}

// ---------------------------------------------------------------------------
// Split w[K=1024][N] into hi/lo bf16 in B-tiled layout:
// [nt:N/128][kt:32][gn:8][khalf:4][c16:16][k8:8]
// ---------------------------------------------------------------------------
__global__ __launch_bounds__(256) void split_w_kernel(
    const float* __restrict__ w, unsigned short* __restrict__ wh,
    unsigned short* __restrict__ wl, int N)
{
    const int t = blockIdx.x * 256 + threadIdx.x;       // N*128 threads
    const int tile = t >> 9, u = t & 511;
    const int nt = tile >> 5, kt = tile & 31;
    const int gn = u >> 6, khalf = (u >> 4) & 3, c16 = u & 15;
    const int n = nt * 128 + gn * 16 + c16;
    const int k0 = kt * 32 + khalf * 8;
    unsigned short h[8], l[8];
    #pragma unroll
    for (int e = 0; e < 8; ++e) {
        const float v = w[(size_t)(k0 + e) * N + n];
        h[e] = f2bf(v);
        l[e] = f2bf(v - bf2f(h[e]));
    }
    uint4 ph, pl;
    ph.x = (unsigned)h[0] | ((unsigned)h[1] << 16);
    ph.y = (unsigned)h[2] | ((unsigned)h[3] << 16);
    ph.z = (unsigned)h[4] | ((unsigned)h[5] << 16);
    ph.w = (unsigned)h[6] | ((unsigned)h[7] << 16);
    pl.x = (unsigned)l[0] | ((unsigned)l[1] << 16);
    pl.y = (unsigned)l[2] | ((unsigned)l[3] << 16);
    pl.z = (unsigned)l[4] | ((unsigned)l[5] << 16);
    pl.w = (unsigned)l[6] | ((unsigned)l[7] << 16);
    *(uint4*)&wh[(size_t)t * 8] = ph;
    *(uint4*)&wl[(size_t)t * 8] = pl;
}

// ---------------------------------------------------------------------------
// Split-bf16 MFMA GEMM, m97 structure: 128x128 tile, BK=32, 4 waves,
// global_load_lds(16B) staging, 2 barriers/K-step, 48 MFMAs/wave/K-step.
// D = Ahi*Bhi + Ahi*Blo + Alo*Bhi  (fp32 accumulate) + bias.
// EPI 0: plain C[m][1024]   EPI 1: qkv scatter to q/k/v head-major.
// ---------------------------------------------------------------------------
template<int EPI>
__global__ __launch_bounds__(256, 2) void mfma_gemm_kernel(
    const unsigned short* __restrict__ Ahg, const unsigned short* __restrict__ Alg,
    const unsigned short* __restrict__ Bhg, const unsigned short* __restrict__ Blg,
    const float* __restrict__ bias,
    float* __restrict__ o0, float* __restrict__ o1, float* __restrict__ o2)
{
    __shared__ unsigned char lds[32768];   // Ahi|Alo|Bhi|Blo, 8KB each
    const int tid = threadIdx.x;
    const int wave = tid >> 6, lane = tid & 63;
    const int bm = blockIdx.y, bn = blockIdx.x;

    // each wave stages exactly one of the four 8KB tiles per K-step
    const unsigned short* mysrc;
    if      (wave == 0) mysrc = Ahg + (size_t)bm * 32 * 4096;
    else if (wave == 1) mysrc = Alg + (size_t)bm * 32 * 4096;
    else if (wave == 2) mysrc = Bhg + (size_t)bn * 32 * 4096;
    else                mysrc = Blg + (size_t)bn * 32 * 4096;

    const f32x4 fzero = {0.f, 0.f, 0.f, 0.f};
    f32x4 acc[4][4];
    #pragma unroll
    for (int i = 0; i < 4; ++i)
        #pragma unroll
        for (int j = 0; j < 4; ++j) acc[i][j] = fzero;

    const int frag_off = ((lane >> 4) << 8) + ((lane & 15) << 4);  // = lane*16
    const int ag = (wave >> 1) * 4;     // A row-group base
    const int bg = (wave & 1) * 4;      // B col-group base

    for (int kt = 0; kt < 32; ++kt) {
        __syncthreads();                // all waves done reading prev LDS
        const unsigned short* src = mysrc + kt * 4096;
        #pragma unroll
        for (int c = 0; c < 8; ++c) {
            const unsigned short* gsrc = src + (c << 9) + (lane << 3);
            __builtin_amdgcn_global_load_lds(
                (gptr_t)(uintptr_t)gsrc,
                (lptr_t)(uintptr_t)(&lds[(wave << 13) + (c << 10)]),
                16, 0, 0);
        }
        __syncthreads();                // barrier drains vmcnt -> LDS valid

        short8 ah[4], al[4], bh[4], bl[4];
        #pragma unroll
        for (int i = 0; i < 4; ++i) {
            const int ao = (ag + i) * 1024 + frag_off;
            const int bo = (bg + i) * 1024 + frag_off;
            ah[i] = __builtin_bit_cast(short8, *(const uint4*)&lds[ao]);
            al[i] = __builtin_bit_cast(short8, *(const uint4*)&lds[8192 + ao]);
            bh[i] = __builtin_bit_cast(short8, *(const uint4*)&lds[16384 + bo]);
            bl[i] = __builtin_bit_cast(short8, *(const uint4*)&lds[24576 + bo]);
        }
        #pragma unroll
        for (int i = 0; i < 4; ++i)
            #pragma unroll
            for (int j = 0; j < 4; ++j) {
                acc[i][j] = __builtin_amdgcn_mfma_f32_16x16x32_bf16(ah[i], bh[j], acc[i][j], 0, 0, 0);
                acc[i][j] = __builtin_amdgcn_mfma_f32_16x16x32_bf16(ah[i], bl[j], acc[i][j], 0, 0, 0);
                acc[i][j] = __builtin_amdgcn_mfma_f32_16x16x32_bf16(al[i], bh[j], acc[i][j], 0, 0, 0);
            }
    }

    // epilogue: C/D layout col=lane&15, row=(lane>>4)*4+reg
    const int gm_base = bm * 128 + (wave >> 1) * 64 + ((lane >> 4) << 2);
    const int gn_base = bn * 128 + (wave & 1) * 64 + (lane & 15);
    #pragma unroll
    for (int j = 0; j < 4; ++j) {
        const int gn = gn_base + j * 16;
        const float bj = bias[gn];
        if (EPI == 0) {
            #pragma unroll
            for (int i = 0; i < 4; ++i)
                #pragma unroll
                for (int r = 0; r < 4; ++r)
                    o0[(size_t)(gm_base + i * 16 + r) * NXDIM + gn] = acc[i][j][r] + bj;
        } else {
            const int sec = gn >> 10;
            const int h   = (gn >> 6) & 15;
            const int d   = gn & 63;
            float* dst = (sec == 0) ? o0 : ((sec == 1) ? o1 : o2);
            #pragma unroll
            for (int i = 0; i < 4; ++i)
                #pragma unroll
                for (int r = 0; r < 4; ++r) {
                    const int gm = gm_base + i * 16 + r;
                    const int b = gm >> 10, s = gm & 1023;
                    dst[((size_t)(b * NHEAD + h) * SEQ + s) * DHEAD + d] = acc[i][j][r] + bj;
                }
        }
    }
}

// ---------------------------------------------------------------------------
// Flash-style causal attention, fp32 vector math.
// Epilogue writes hi/lo bf16 directly in proj-A tiled layout.
// ---------------------------------------------------------------------------
__global__ __launch_bounds__(256) void attn_kernel(
    const float* __restrict__ qbuf, const float* __restrict__ kbuf,
    const float* __restrict__ vbuf, unsigned short* __restrict__ ahi,
    unsigned short* __restrict__ alo)
{
    __shared__ float QsT[64][64];
    __shared__ float KsT[64][64];
    __shared__ float Vs[64][64];
    __shared__ float PsT[64][64];

    const int tid = threadIdx.x;
    const int tx = tid & 15, ty = tid >> 4;
    const int qt = 15 - (int)(blockIdx.x & 15);   // heavy q-tiles first
    const int bh = blockIdx.x >> 4;
    const int b = bh >> 4, h = bh & 15;
    const int q0 = qt << 6;

    const float* qb = qbuf + (size_t)bh * SEQ * DHEAD;
    const float* kb = kbuf + (size_t)bh * SEQ * DHEAD;
    const float* vb = vbuf + (size_t)bh * SEQ * DHEAD;

    {
        const int r0 = tid >> 4;
        const int c  = (tid & 15) << 2;
        #pragma unroll
        for (int i = 0; i < 4; ++i) {
            const int r = r0 + (i << 4);
            const float4 qv = *(const float4*)&qb[(size_t)(q0 + r) * DHEAD + c];
            QsT[c + 0][r] = qv.x;
            QsT[c + 1][r] = qv.y;
            QsT[c + 2][r] = qv.z;
            QsT[c + 3][r] = qv.w;
        }
    }

    float mprev[4], lsum[4], oacc[4][4];
    #pragma unroll
    for (int i = 0; i < 4; ++i) {
        mprev[i] = -3.0e38f;
        lsum[i] = 0.f;
        #pragma unroll
        for (int j = 0; j < 4; ++j) oacc[i][j] = 0.f;
    }

    for (int kt = 0; kt <= qt; ++kt) {
        const int k0 = kt << 6;
        __syncthreads();
        {
            const int r0 = tid >> 4;
            const int c  = (tid & 15) << 2;
            #pragma unroll
            for (int i = 0; i < 4; ++i) {
                const int r = r0 + (i << 4);
                const float4 kv = *(const float4*)&kb[(size_t)(k0 + r) * DHEAD + c];
                KsT[c + 0][r] = kv.x;
                KsT[c + 1][r] = kv.y;
                KsT[c + 2][r] = kv.z;
                KsT[c + 3][r] = kv.w;
                *(float4*)&Vs[r][c] = *(const float4*)&vb[(size_t)(k0 + r) * DHEAD + c];
            }
        }
        __syncthreads();

        float sacc[4][4] = {};
        #pragma unroll 16
        for (int d = 0; d < 64; ++d) {
            const float4 a4 = *(const float4*)&QsT[d][ty << 2];
            const float4 b4 = *(const float4*)&KsT[d][tx << 2];
            const float ar[4] = {a4.x, a4.y, a4.z, a4.w};
            const float br[4] = {b4.x, b4.y, b4.z, b4.w};
            #pragma unroll
            for (int i = 0; i < 4; ++i)
                #pragma unroll
                for (int j = 0; j < 4; ++j)
                    sacc[i][j] = fmaf(ar[i], br[j], sacc[i][j]);
        }

        const bool diag = (kt == qt);
        #pragma unroll
        for (int i = 0; i < 4; ++i) {
            const int rq = q0 + (ty << 2) + i;
            float mx = -3.0e38f;
            #pragma unroll
            for (int j = 0; j < 4; ++j) {
                float sv = sacc[i][j] * 0.125f;                    // 1/sqrt(64)
                if (diag && (k0 + (tx << 2) + j) > rq) sv = -1.0e9f;
                sacc[i][j] = sv;
                mx = fmaxf(mx, sv);
            }
            mx = fmaxf(mx, __shfl_xor(mx, 1));
            mx = fmaxf(mx, __shfl_xor(mx, 2));
            mx = fmaxf(mx, __shfl_xor(mx, 4));
            mx = fmaxf(mx, __shfl_xor(mx, 8));
            const float mnew = fmaxf(mprev[i], mx);
            const float corr = __expf(mprev[i] - mnew);
            float rsum = 0.f;
            #pragma unroll
            for (int j = 0; j < 4; ++j) {
                const float p = __expf(sacc[i][j] - mnew);  // masked -> 0
                sacc[i][j] = p;
                rsum += p;
            }
            rsum += __shfl_xor(rsum, 1);
            rsum += __shfl_xor(rsum, 2);
            rsum += __shfl_xor(rsum, 4);
            rsum += __shfl_xor(rsum, 8);
            lsum[i] = lsum[i] * corr + rsum;
            mprev[i] = mnew;
            #pragma unroll
            for (int j = 0; j < 4; ++j) oacc[i][j] *= corr;
        }

        #pragma unroll
        for (int j = 0; j < 4; ++j) {
            float4 pv;
            pv.x = sacc[0][j]; pv.y = sacc[1][j]; pv.z = sacc[2][j]; pv.w = sacc[3][j];
            *(float4*)&PsT[(tx << 2) + j][ty << 2] = pv;
        }
        __syncthreads();

        #pragma unroll 16
        for (int kk = 0; kk < 64; ++kk) {
            const float4 a4 = *(const float4*)&PsT[kk][ty << 2];
            const float4 b4 = *(const float4*)&Vs[kk][tx << 2];
            const float ar[4] = {a4.x, a4.y, a4.z, a4.w};
            const float br[4] = {b4.x, b4.y, b4.z, b4.w};
            #pragma unroll
            for (int i = 0; i < 4; ++i)
                #pragma unroll
                for (int j = 0; j < 4; ++j)
                    oacc[i][j] = fmaf(ar[i], br[j], oacc[i][j]);
        }
    }

    // epilogue: normalize, split hi/lo bf16, write in proj-A tiled layout
    const int dcol = tx << 2;
    const int kcol = h * 64 + dcol;
    const int ktile = kcol >> 5, khalf = (kcol & 31) >> 3, k7 = kcol & 7;
    #pragma unroll
    for (int i = 0; i < 4; ++i) {
        const int srow = q0 + (ty << 2) + i;
        const int m = b * 1024 + srow;
        const float inv = 1.0f / lsum[i];
        const size_t off = ((size_t)((m >> 7) * 32 + ktile) << 12)
                         + (size_t)((((m & 127) >> 4) << 9) + (khalf << 7) + ((m & 15) << 3) + k7);
        float o[4];
        #pragma unroll
        for (int j = 0; j < 4; ++j) o[j] = oacc[i][j] * inv;
        ushort4 hh, ll;
        hh.x = f2bf(o[0]); ll.x = f2bf(o[0] - bf2f(hh.x));
        hh.y = f2bf(o[1]); ll.y = f2bf(o[1] - bf2f(hh.y));
        hh.z = f2bf(o[2]); ll.z = f2bf(o[2] - bf2f(hh.z));
        hh.w = f2bf(o[3]); ll.w = f2bf(o[3] - bf2f(hh.w));
        *(ushort4*)&ahi[off] = hh;
        *(ushort4*)&alo[off] = ll;
    }
}

extern "C" void kernel_launch(void* const* d_in, const int* in_sizes, int n_in,
                              void* d_out, int out_size, void* d_ws, size_t ws_size,
                              hipStream_t stream) {
    const float* x      = (const float*)d_in[0];
    // d_in[1] = causal mask — analytic, ignored
    const float* w_attn = (const float*)d_in[2];
    const float* b_attn = (const float*)d_in[3];
    const float* w_proj = (const float*)d_in[4];
    const float* b_proj = (const float*)d_in[5];

    float* out = (float*)d_out;
    float* kbuf = out + (size_t)BATCH * SEQ * NXDIM;            // present: k
    float* vbuf = kbuf + (size_t)BATCH * NHEAD * SEQ * DHEAD;   // present: v
    // q lives in the `a` region of d_out (dead until proj writes it)
    float* qbuf = out;

    unsigned char* ws = (unsigned char*)d_ws;                   // 32 MB used
    unsigned short* xh  = (unsigned short*)(ws);                // 8 MB
    unsigned short* xl  = (unsigned short*)(ws + (8u  << 20));  // 8 MB
    unsigned short* wah = (unsigned short*)(ws + (16u << 20));  // 6 MB
    unsigned short* wal = (unsigned short*)(ws + (22u << 20));  // 6 MB
    unsigned short* wph = (unsigned short*)(ws + (28u << 20));  // 2 MB
    unsigned short* wpl = (unsigned short*)(ws + (30u << 20));  // 2 MB
    unsigned short* ah  = xh;   // x-split dead after qkv gemm — reuse
    unsigned short* al  = xl;

    split_x_kernel<<<2048, 256, 0, stream>>>(x, xh, xl);
    split_w_kernel<<<1536, 256, 0, stream>>>(w_attn, wah, wal, QKVN);
    split_w_kernel<<<512,  256, 0, stream>>>(w_proj, wph, wpl, NXDIM);
    mfma_gemm_kernel<1><<<dim3(24, 32), 256, 0, stream>>>(
        xh, xl, wah, wal, b_attn, qbuf, kbuf, vbuf);
    attn_kernel<<<1024, 256, 0, stream>>>(qbuf, kbuf, vbuf, ah, al);
    mfma_gemm_kernel<0><<<dim3(8, 32), 256, 0, stream>>>(
        ah, al, wph, wpl, b_proj, out, nullptr, nullptr);
}

// Round 5
// 516.394 us; speedup vs baseline: 1.0076x; 1.0076x over previous
//
#include <hip/hip_runtime.h>
#include <math.h>
#include <stdint.h>

#define BATCH 4
#define SEQ   1024
#define NXDIM 1024
#define NHEAD 16
#define DHEAD 64
#define QKVN  3072
#define MROWS 4096
#define KDIM  1024

typedef short short8 __attribute__((ext_vector_type(8)));   // 8 x bf16 bits
typedef float f32x4  __attribute__((ext_vector_type(4)));

typedef const __attribute__((address_space(1))) unsigned int* gptr_t;
typedef __attribute__((address_space(3))) unsigned int* lptr_t;

__device__ __forceinline__ unsigned short f2bf(float f) {
    unsigned int u = __float_as_uint(f);
    u += 0x7FFF + ((u >> 16) & 1);          // round-to-nearest-even
    return (unsigned short)(u >> 16);
}
__device__ __forceinline__ float bf2f(unsigned short h) {
    return __uint_as_float(((unsigned int)h) << 16);
}

// XOR-swizzled dword index into a 64x64 LDS tile stored [d][r]:
// writes (16 lanes same r, varying d=c+e) spread over 8 banks -> 2-way floor;
// float4 reads at fixed d stay 16 distinct 16B chunks -> floor.
__device__ __forceinline__ int swz(int d, int r) {
    return d * 64 + (r ^ (((d >> 2) & 7) << 2));
}

// ---------------------------------------------------------------------------
// Split x (M=4096, K=1024, row-major) into hi/lo bf16 in A-tiled layout:
// [mt:32][kt:32][g:8][khalf:4][r16:16][k8:8]  (tile = 4096 elems = 8 KB)
// ---------------------------------------------------------------------------
__global__ __launch_bounds__(256) void split_x_kernel(
    const float* __restrict__ x, unsigned short* __restrict__ xh,
    unsigned short* __restrict__ xl)
{
    const int t = blockIdx.x * 256 + threadIdx.x;       // 524288 threads
    const int tile = t >> 9, u = t & 511;
    const int mt = tile >> 5, kt = tile & 31;
    const int g = u >> 6, khalf = (u >> 4) & 3, r16 = u & 15;
    const int m = mt * 128 + g * 16 + r16;
    const int k = kt * 32 + khalf * 8;
    const float4 v0 = *(const float4*)&x[(size_t)m * KDIM + k];
    const float4 v1 = *(const float4*)&x[(size_t)m * KDIM + k + 4];
    const float vv[8] = {v0.x, v0.y, v0.z, v0.w, v1.x, v1.y, v1.z, v1.w};
    unsigned short h[8], l[8];
    #pragma unroll
    for (int e = 0; e < 8; ++e) {
        h[e] = f2bf(vv[e]);
        l[e] = f2bf(vv[e] - bf2f(h[e]));
    }
    uint4 ph, pl;
    ph.x = (unsigned)h[0] | ((unsigned)h[1] << 16);
    ph.y = (unsigned)h[2] | ((unsigned)h[3] << 16);
    ph.z = (unsigned)h[4] | ((unsigned)h[5] << 16);
    ph.w = (unsigned)h[6] | ((unsigned)h[7] << 16);
    pl.x = (unsigned)l[0] | ((unsigned)l[1] << 16);
    pl.y = (unsigned)l[2] | ((unsigned)l[3] << 16);
    pl.z = (unsigned)l[4] | ((unsigned)l[5] << 16);
    pl.w = (unsigned)l[6] | ((unsigned)l[7] << 16);
    *(uint4*)&xh[(size_t)t * 8] = ph;
    *(uint4*)&xl[(size_t)t * 8] = pl;
}

// ---------------------------------------------------------------------------
// Split w[K=1024][N] into hi/lo bf16 in B-tiled layout:
// [nt:N/128][kt:32][gn:8][khalf:4][c16:16][k8:8]
// ---------------------------------------------------------------------------
__global__ __launch_bounds__(256) void split_w_kernel(
    const float* __restrict__ w, unsigned short* __restrict__ wh,
    unsigned short* __restrict__ wl, int N)
{
    const int t = blockIdx.x * 256 + threadIdx.x;       // N*128 threads
    const int tile = t >> 9, u = t & 511;
    const int nt = tile >> 5, kt = tile & 31;
    const int gn = u >> 6, khalf = (u >> 4) & 3, c16 = u & 15;
    const int n = nt * 128 + gn * 16 + c16;
    const int k0 = kt * 32 + khalf * 8;
    unsigned short h[8], l[8];
    #pragma unroll
    for (int e = 0; e < 8; ++e) {
        const float v = w[(size_t)(k0 + e) * N + n];
        h[e] = f2bf(v);
        l[e] = f2bf(v - bf2f(h[e]));
    }
    uint4 ph, pl;
    ph.x = (unsigned)h[0] | ((unsigned)h[1] << 16);
    ph.y = (unsigned)h[2] | ((unsigned)h[3] << 16);
    ph.z = (unsigned)h[4] | ((unsigned)h[5] << 16);
    ph.w = (unsigned)h[6] | ((unsigned)h[7] << 16);
    pl.x = (unsigned)l[0] | ((unsigned)l[1] << 16);
    pl.y = (unsigned)l[2] | ((unsigned)l[3] << 16);
    pl.z = (unsigned)l[4] | ((unsigned)l[5] << 16);
    pl.w = (unsigned)l[6] | ((unsigned)l[7] << 16);
    *(uint4*)&wh[(size_t)t * 8] = ph;
    *(uint4*)&wl[(size_t)t * 8] = pl;
}

// ---------------------------------------------------------------------------
// Split-bf16 MFMA GEMM, m97 structure: 128x128 tile, BK=32, 4 waves,
// global_load_lds(16B) staging, 2 barriers/K-step, 48 MFMAs/wave/K-step.
// D = Ahi*Bhi + Ahi*Blo + Alo*Bhi  (fp32 accumulate) + bias.
// EPI 0: plain C[m][1024]   EPI 1: qkv scatter to q/k/v head-major.
// ---------------------------------------------------------------------------
template<int EPI>
__global__ __launch_bounds__(256, 2) void mfma_gemm_kernel(
    const unsigned short* __restrict__ Ahg, const unsigned short* __restrict__ Alg,
    const unsigned short* __restrict__ Bhg, const unsigned short* __restrict__ Blg,
    const float* __restrict__ bias,
    float* __restrict__ o0, float* __restrict__ o1, float* __restrict__ o2)
{
    __shared__ unsigned char lds[32768];   // Ahi|Alo|Bhi|Blo, 8KB each
    const int tid = threadIdx.x;
    const int wave = tid >> 6, lane = tid & 63;
    const int bm = blockIdx.y, bn = blockIdx.x;

    // each wave stages exactly one of the four 8KB tiles per K-step
    const unsigned short* mysrc;
    if      (wave == 0) mysrc = Ahg + (size_t)bm * 32 * 4096;
    else if (wave == 1) mysrc = Alg + (size_t)bm * 32 * 4096;
    else if (wave == 2) mysrc = Bhg + (size_t)bn * 32 * 4096;
    else                mysrc = Blg + (size_t)bn * 32 * 4096;

    const f32x4 fzero = {0.f, 0.f, 0.f, 0.f};
    f32x4 acc[4][4];
    #pragma unroll
    for (int i = 0; i < 4; ++i)
        #pragma unroll
        for (int j = 0; j < 4; ++j) acc[i][j] = fzero;

    const int frag_off = ((lane >> 4) << 8) + ((lane & 15) << 4);  // = lane*16
    const int ag = (wave >> 1) * 4;     // A row-group base
    const int bg = (wave & 1) * 4;      // B col-group base

    for (int kt = 0; kt < 32; ++kt) {
        __syncthreads();                // all waves done reading prev LDS
        const unsigned short* src = mysrc + kt * 4096;
        #pragma unroll
        for (int c = 0; c < 8; ++c) {
            const unsigned short* gsrc = src + (c << 9) + (lane << 3);
            __builtin_amdgcn_global_load_lds(
                (gptr_t)(uintptr_t)gsrc,
                (lptr_t)(uintptr_t)(&lds[(wave << 13) + (c << 10)]),
                16, 0, 0);
        }
        __syncthreads();                // barrier drains vmcnt -> LDS valid

        short8 ah[4], al[4], bh[4], bl[4];
        #pragma unroll
        for (int i = 0; i < 4; ++i) {
            const int ao = (ag + i) * 1024 + frag_off;
            const int bo = (bg + i) * 1024 + frag_off;
            ah[i] = __builtin_bit_cast(short8, *(const uint4*)&lds[ao]);
            al[i] = __builtin_bit_cast(short8, *(const uint4*)&lds[8192 + ao]);
            bh[i] = __builtin_bit_cast(short8, *(const uint4*)&lds[16384 + bo]);
            bl[i] = __builtin_bit_cast(short8, *(const uint4*)&lds[24576 + bo]);
        }
        #pragma unroll
        for (int i = 0; i < 4; ++i)
            #pragma unroll
            for (int j = 0; j < 4; ++j) {
                acc[i][j] = __builtin_amdgcn_mfma_f32_16x16x32_bf16(ah[i], bh[j], acc[i][j], 0, 0, 0);
                acc[i][j] = __builtin_amdgcn_mfma_f32_16x16x32_bf16(ah[i], bl[j], acc[i][j], 0, 0, 0);
                acc[i][j] = __builtin_amdgcn_mfma_f32_16x16x32_bf16(al[i], bh[j], acc[i][j], 0, 0, 0);
            }
    }

    // epilogue: C/D layout col=lane&15, row=(lane>>4)*4+reg
    const int gm_base = bm * 128 + (wave >> 1) * 64 + ((lane >> 4) << 2);
    const int gn_base = bn * 128 + (wave & 1) * 64 + (lane & 15);
    #pragma unroll
    for (int j = 0; j < 4; ++j) {
        const int gn = gn_base + j * 16;
        const float bj = bias[gn];
        if (EPI == 0) {
            #pragma unroll
            for (int i = 0; i < 4; ++i)
                #pragma unroll
                for (int r = 0; r < 4; ++r)
                    o0[(size_t)(gm_base + i * 16 + r) * NXDIM + gn] = acc[i][j][r] + bj;
        } else {
            const int sec = gn >> 10;
            const int h   = (gn >> 6) & 15;
            const int d   = gn & 63;
            float* dst = (sec == 0) ? o0 : ((sec == 1) ? o1 : o2);
            #pragma unroll
            for (int i = 0; i < 4; ++i)
                #pragma unroll
                for (int r = 0; r < 4; ++r) {
                    const int gm = gm_base + i * 16 + r;
                    const int b = gm >> 10, s = gm & 1023;
                    dst[((size_t)(b * NHEAD + h) * SEQ + s) * DHEAD + d] = acc[i][j][r] + bj;
                }
        }
    }
}

// ---------------------------------------------------------------------------
// Flash-style causal attention, fp32 vector math.
// R5: XOR-swizzled QsT/KsT (kills 16-way staging-write conflicts) +
//     register prefetch of next K/V tile (hides HBM latency under compute) +
//     Q pre-scaled by 1/sqrt(D) at staging.
// Epilogue writes hi/lo bf16 directly in proj-A tiled layout.
// ---------------------------------------------------------------------------
__global__ __launch_bounds__(256) void attn_kernel(
    const float* __restrict__ qbuf, const float* __restrict__ kbuf,
    const float* __restrict__ vbuf, unsigned short* __restrict__ ahi,
    unsigned short* __restrict__ alo)
{
    __shared__ float QsT[4096];     // swizzled [d][r]
    __shared__ float KsT[4096];     // swizzled [d][r]
    __shared__ float Vs[64][64];    // row-major [r][d]
    __shared__ float PsT[64][64];   // [j][i]

    const int tid = threadIdx.x;
    const int tx = tid & 15, ty = tid >> 4;
    const int qt = 15 - (int)(blockIdx.x & 15);   // heavy q-tiles first
    const int bh = blockIdx.x >> 4;
    const int b = bh >> 4, h = bh & 15;
    const int q0 = qt << 6;

    const float* qb = qbuf + (size_t)bh * SEQ * DHEAD;
    const float* kb = kbuf + (size_t)bh * SEQ * DHEAD;
    const float* vb = vbuf + (size_t)bh * SEQ * DHEAD;

    const int r0 = tid >> 4;            // 0..15
    const int c  = (tid & 15) << 2;     // 0,4,..,60

    // stage Q (transposed, swizzled, pre-scaled by 1/8)
    #pragma unroll
    for (int i = 0; i < 4; ++i) {
        const int r = r0 + (i << 4);
        const float4 qv = *(const float4*)&qb[(size_t)(q0 + r) * DHEAD + c];
        QsT[swz(c + 0, r)] = qv.x * 0.125f;
        QsT[swz(c + 1, r)] = qv.y * 0.125f;
        QsT[swz(c + 2, r)] = qv.z * 0.125f;
        QsT[swz(c + 3, r)] = qv.w * 0.125f;
    }

    // prefetch tile 0 into registers, then commit to LDS
    float4 kreg[4], vreg[4];
    #pragma unroll
    for (int i = 0; i < 4; ++i) {
        const int r = r0 + (i << 4);
        kreg[i] = *(const float4*)&kb[(size_t)r * DHEAD + c];
        vreg[i] = *(const float4*)&vb[(size_t)r * DHEAD + c];
    }
    #pragma unroll
    for (int i = 0; i < 4; ++i) {
        const int r = r0 + (i << 4);
        KsT[swz(c + 0, r)] = kreg[i].x;
        KsT[swz(c + 1, r)] = kreg[i].y;
        KsT[swz(c + 2, r)] = kreg[i].z;
        KsT[swz(c + 3, r)] = kreg[i].w;
        *(float4*)&Vs[r][c] = vreg[i];
    }

    float mprev[4], lsum[4], oacc[4][4];
    #pragma unroll
    for (int i = 0; i < 4; ++i) {
        mprev[i] = -3.0e38f;
        lsum[i] = 0.f;
        #pragma unroll
        for (int j = 0; j < 4; ++j) oacc[i][j] = 0.f;
    }

    for (int kt = 0; kt <= qt; ++kt) {
        __syncthreads();    // K/V (and Q on iter 0) writes visible

        // issue next tile's global loads early — hidden under compute
        if (kt < qt) {
            const int k1 = (kt + 1) << 6;
            #pragma unroll
            for (int i = 0; i < 4; ++i) {
                const int r = r0 + (i << 4);
                kreg[i] = *(const float4*)&kb[(size_t)(k1 + r) * DHEAD + c];
                vreg[i] = *(const float4*)&vb[(size_t)(k1 + r) * DHEAD + c];
            }
        }

        // scores: s[i][j] = sum_d Qs[q0+4ty+i][d] * Ks[4tx+j][d]
        float sacc[4][4] = {};
        #pragma unroll 16
        for (int d = 0; d < 64; ++d) {
            const int key = ((d >> 2) & 7) << 2;
            const float4 a4 = *(const float4*)&QsT[d * 64 + ((ty << 2) ^ key)];
            const float4 b4 = *(const float4*)&KsT[d * 64 + ((tx << 2) ^ key)];
            const float ar[4] = {a4.x, a4.y, a4.z, a4.w};
            const float br[4] = {b4.x, b4.y, b4.z, b4.w};
            #pragma unroll
            for (int i = 0; i < 4; ++i)
                #pragma unroll
                for (int j = 0; j < 4; ++j)
                    sacc[i][j] = fmaf(ar[i], br[j], sacc[i][j]);
        }

        const int k0 = kt << 6;
        const bool diag = (kt == qt);
        #pragma unroll
        for (int i = 0; i < 4; ++i) {
            const int rq = q0 + (ty << 2) + i;
            float mx = -3.0e38f;
            #pragma unroll
            for (int j = 0; j < 4; ++j) {
                float sv = sacc[i][j];                 // Q pre-scaled
                if (diag && (k0 + (tx << 2) + j) > rq) sv = -1.0e9f;
                sacc[i][j] = sv;
                mx = fmaxf(mx, sv);
            }
            mx = fmaxf(mx, __shfl_xor(mx, 1));
            mx = fmaxf(mx, __shfl_xor(mx, 2));
            mx = fmaxf(mx, __shfl_xor(mx, 4));
            mx = fmaxf(mx, __shfl_xor(mx, 8));
            const float mnew = fmaxf(mprev[i], mx);
            const float corr = __expf(mprev[i] - mnew);
            float rsum = 0.f;
            #pragma unroll
            for (int j = 0; j < 4; ++j) {
                const float p = __expf(sacc[i][j] - mnew);  // masked -> 0
                sacc[i][j] = p;
                rsum += p;
            }
            rsum += __shfl_xor(rsum, 1);
            rsum += __shfl_xor(rsum, 2);
            rsum += __shfl_xor(rsum, 4);
            rsum += __shfl_xor(rsum, 8);
            lsum[i] = lsum[i] * corr + rsum;
            mprev[i] = mnew;
            #pragma unroll
            for (int j = 0; j < 4; ++j) oacc[i][j] *= corr;
        }

        #pragma unroll
        for (int j = 0; j < 4; ++j) {
            float4 pv;
            pv.x = sacc[0][j]; pv.y = sacc[1][j]; pv.z = sacc[2][j]; pv.w = sacc[3][j];
            *(float4*)&PsT[(tx << 2) + j][ty << 2] = pv;
        }
        __syncthreads();

        // o[i][d] += sum_j P[i][j] * V[j][d]
        #pragma unroll 16
        for (int kk = 0; kk < 64; ++kk) {
            const float4 a4 = *(const float4*)&PsT[kk][ty << 2];
            const float4 b4 = *(const float4*)&Vs[kk][tx << 2];
            const float ar[4] = {a4.x, a4.y, a4.z, a4.w};
            const float br[4] = {b4.x, b4.y, b4.z, b4.w};
            #pragma unroll
            for (int i = 0; i < 4; ++i)
                #pragma unroll
                for (int j = 0; j < 4; ++j)
                    oacc[i][j] = fmaf(ar[i], br[j], oacc[i][j]);
        }
        __syncthreads();    // all reads of KsT/Vs done

        // commit prefetched tile to LDS
        if (kt < qt) {
            #pragma unroll
            for (int i = 0; i < 4; ++i) {
                const int r = r0 + (i << 4);
                KsT[swz(c + 0, r)] = kreg[i].x;
                KsT[swz(c + 1, r)] = kreg[i].y;
                KsT[swz(c + 2, r)] = kreg[i].z;
                KsT[swz(c + 3, r)] = kreg[i].w;
                *(float4*)&Vs[r][c] = vreg[i];
            }
        }
    }

    // epilogue: normalize, split hi/lo bf16, write in proj-A tiled layout
    const int dcol = tx << 2;
    const int kcol = h * 64 + dcol;
    const int ktile = kcol >> 5, khalf = (kcol & 31) >> 3, k7 = kcol & 7;
    #pragma unroll
    for (int i = 0; i < 4; ++i) {
        const int srow = q0 + (ty << 2) + i;
        const int m = b * 1024 + srow;
        const float inv = 1.0f / lsum[i];
        const size_t off = ((size_t)((m >> 7) * 32 + ktile) << 12)
                         + (size_t)((((m & 127) >> 4) << 9) + (khalf << 7) + ((m & 15) << 3) + k7);
        float o[4];
        #pragma unroll
        for (int j = 0; j < 4; ++j) o[j] = oacc[i][j] * inv;
        ushort4 hh, ll;
        hh.x = f2bf(o[0]); ll.x = f2bf(o[0] - bf2f(hh.x));
        hh.y = f2bf(o[1]); ll.y = f2bf(o[1] - bf2f(hh.y));
        hh.z = f2bf(o[2]); ll.z = f2bf(o[2] - bf2f(hh.z));
        hh.w = f2bf(o[3]); ll.w = f2bf(o[3] - bf2f(hh.w));
        *(ushort4*)&ahi[off] = hh;
        *(ushort4*)&alo[off] = ll;
    }
}

extern "C" void kernel_launch(void* const* d_in, const int* in_sizes, int n_in,
                              void* d_out, int out_size, void* d_ws, size_t ws_size,
                              hipStream_t stream) {
    const float* x      = (const float*)d_in[0];
    // d_in[1] = causal mask — analytic, ignored
    const float* w_attn = (const float*)d_in[2];
    const float* b_attn = (const float*)d_in[3];
    const float* w_proj = (const float*)d_in[4];
    const float* b_proj = (const float*)d_in[5];

    float* out = (float*)d_out;
    float* kbuf = out + (size_t)BATCH * SEQ * NXDIM;            // present: k
    float* vbuf = kbuf + (size_t)BATCH * NHEAD * SEQ * DHEAD;   // present: v
    // q lives in the `a` region of d_out (dead until proj writes it)
    float* qbuf = out;

    unsigned char* ws = (unsigned char*)d_ws;                   // 32 MB used
    unsigned short* xh  = (unsigned short*)(ws);                // 8 MB
    unsigned short* xl  = (unsigned short*)(ws + (8u  << 20));  // 8 MB
    unsigned short* wah = (unsigned short*)(ws + (16u << 20));  // 6 MB
    unsigned short* wal = (unsigned short*)(ws + (22u << 20));  // 6 MB
    unsigned short* wph = (unsigned short*)(ws + (28u << 20));  // 2 MB
    unsigned short* wpl = (unsigned short*)(ws + (30u << 20));  // 2 MB
    unsigned short* ah  = xh;   // x-split dead after qkv gemm — reuse
    unsigned short* al  = xl;

    split_x_kernel<<<2048, 256, 0, stream>>>(x, xh, xl);
    split_w_kernel<<<1536, 256, 0, stream>>>(w_attn, wah, wal, QKVN);
    split_w_kernel<<<512,  256, 0, stream>>>(w_proj, wph, wpl, NXDIM);
    mfma_gemm_kernel<1><<<dim3(24, 32), 256, 0, stream>>>(
        xh, xl, wah, wal, b_attn, qbuf, kbuf, vbuf);
    attn_kernel<<<1024, 256, 0, stream>>>(qbuf, kbuf, vbuf, ah, al);
    mfma_gemm_kernel<0><<<dim3(8, 32), 256, 0, stream>>>(
        ah, al, wph, wpl, b_proj, out, nullptr, nullptr);
}

// Round 6
// 320.072 us; speedup vs baseline: 1.6257x; 1.6134x over previous
//
#include <hip/hip_runtime.h>
#include <math.h>
#include <stdint.h>

#define BATCH 4
#define SEQ   1024
#define NXDIM 1024
#define NHEAD 16
#define DHEAD 64
#define QKVN  3072
#define MROWS 4096
#define KDIM  1024

typedef short short8 __attribute__((ext_vector_type(8)));   // 8 x bf16 bits
typedef float f32x4  __attribute__((ext_vector_type(4)));

typedef const __attribute__((address_space(1))) unsigned int* gptr_t;
typedef __attribute__((address_space(3))) unsigned int* lptr_t;

__device__ __forceinline__ unsigned short f2bf(float f) {
    unsigned int u = __float_as_uint(f);
    u += 0x7FFF + ((u >> 16) & 1);          // round-to-nearest-even
    return (unsigned short)(u >> 16);
}
__device__ __forceinline__ float bf2f(unsigned short h) {
    return __uint_as_float(((unsigned int)h) << 16);
}
// pack two floats' RTNE-bf16 into one uint (a in low half)
__device__ __forceinline__ unsigned pk_hi_rtne(float a, float b) {
    unsigned ua = __float_as_uint(a), ub = __float_as_uint(b);
    ua += 0x7FFF + ((ua >> 16) & 1);
    ub += 0x7FFF + ((ub >> 16) & 1);
    return __builtin_amdgcn_perm(ub, ua, 0x07060302u);
}
// pack two floats' trunc-bf16 into one uint
__device__ __forceinline__ unsigned pk_hi_trunc(float a, float b) {
    return __builtin_amdgcn_perm(__float_as_uint(b), __float_as_uint(a), 0x07060302u);
}
__device__ __forceinline__ float trunc_bf(float a) {
    return __uint_as_float(__float_as_uint(a) & 0xFFFF0000u);
}
__device__ __forceinline__ float rtne_bf(float a) {
    unsigned u = __float_as_uint(a);
    u += 0x7FFF + ((u >> 16) & 1);
    return __uint_as_float(u & 0xFFFF0000u);
}

// ---------------------------------------------------------------------------
// Split x (M=4096, K=1024, row-major) into hi/lo bf16 in A-tiled layout:
// [mt:32][kt:32][g:8][khalf:4][r16:16][k8:8]  (tile = 4096 elems = 8 KB)
// ---------------------------------------------------------------------------
__global__ __launch_bounds__(256) void split_x_kernel(
    const float* __restrict__ x, unsigned short* __restrict__ xh,
    unsigned short* __restrict__ xl)
{
    const int t = blockIdx.x * 256 + threadIdx.x;       // 524288 threads
    const int tile = t >> 9, u = t & 511;
    const int mt = tile >> 5, kt = tile & 31;
    const int g = u >> 6, khalf = (u >> 4) & 3, r16 = u & 15;
    const int m = mt * 128 + g * 16 + r16;
    const int k = kt * 32 + khalf * 8;
    const float4 v0 = *(const float4*)&x[(size_t)m * KDIM + k];
    const float4 v1 = *(const float4*)&x[(size_t)m * KDIM + k + 4];
    const float vv[8] = {v0.x, v0.y, v0.z, v0.w, v1.x, v1.y, v1.z, v1.w};
    unsigned short h[8], l[8];
    #pragma unroll
    for (int e = 0; e < 8; ++e) {
        h[e] = f2bf(vv[e]);
        l[e] = f2bf(vv[e] - bf2f(h[e]));
    }
    uint4 ph, pl;
    ph.x = (unsigned)h[0] | ((unsigned)h[1] << 16);
    ph.y = (unsigned)h[2] | ((unsigned)h[3] << 16);
    ph.z = (unsigned)h[4] | ((unsigned)h[5] << 16);
    ph.w = (unsigned)h[6] | ((unsigned)h[7] << 16);
    pl.x = (unsigned)l[0] | ((unsigned)l[1] << 16);
    pl.y = (unsigned)l[2] | ((unsigned)l[3] << 16);
    pl.z = (unsigned)l[4] | ((unsigned)l[5] << 16);
    pl.w = (unsigned)l[6] | ((unsigned)l[7] << 16);
    *(uint4*)&xh[(size_t)t * 8] = ph;
    *(uint4*)&xl[(size_t)t * 8] = pl;
}

// ---------------------------------------------------------------------------
// Split w[K=1024][N] into hi/lo bf16 in B-tiled layout:
// [nt:N/128][kt:32][gn:8][khalf:4][c16:16][k8:8]
// ---------------------------------------------------------------------------
__global__ __launch_bounds__(256) void split_w_kernel(
    const float* __restrict__ w, unsigned short* __restrict__ wh,
    unsigned short* __restrict__ wl, int N)
{
    const int t = blockIdx.x * 256 + threadIdx.x;       // N*128 threads
    const int tile = t >> 9, u = t & 511;
    const int nt = tile >> 5, kt = tile & 31;
    const int gn = u >> 6, khalf = (u >> 4) & 3, c16 = u & 15;
    const int n = nt * 128 + gn * 16 + c16;
    const int k0 = kt * 32 + khalf * 8;
    unsigned short h[8], l[8];
    #pragma unroll
    for (int e = 0; e < 8; ++e) {
        const float v = w[(size_t)(k0 + e) * N + n];
        h[e] = f2bf(v);
        l[e] = f2bf(v - bf2f(h[e]));
    }
    uint4 ph, pl;
    ph.x = (unsigned)h[0] | ((unsigned)h[1] << 16);
    ph.y = (unsigned)h[2] | ((unsigned)h[3] << 16);
    ph.z = (unsigned)h[4] | ((unsigned)h[5] << 16);
    ph.w = (unsigned)h[6] | ((unsigned)h[7] << 16);
    pl.x = (unsigned)l[0] | ((unsigned)l[1] << 16);
    pl.y = (unsigned)l[2] | ((unsigned)l[3] << 16);
    pl.z = (unsigned)l[4] | ((unsigned)l[5] << 16);
    pl.w = (unsigned)l[6] | ((unsigned)l[7] << 16);
    *(uint4*)&wh[(size_t)t * 8] = ph;
    *(uint4*)&wl[(size_t)t * 8] = pl;
}

// ---------------------------------------------------------------------------
// Split-bf16 MFMA GEMM, m97 structure: 128x128 tile, BK=32, 4 waves.
// D = Ahi*Bhi + Ahi*Blo + Alo*Bhi  (fp32 accumulate) + bias.
// EPI 0: plain C[m][1024]
// EPI 1: qkv scatter — q as pre-scaled hi/lo bf16, k/v fp32 head-major.
// ---------------------------------------------------------------------------
template<int EPI>
__global__ __launch_bounds__(256, 2) void mfma_gemm_kernel(
    const unsigned short* __restrict__ Ahg, const unsigned short* __restrict__ Alg,
    const unsigned short* __restrict__ Bhg, const unsigned short* __restrict__ Blg,
    const float* __restrict__ bias,
    float* __restrict__ o0, float* __restrict__ o1, float* __restrict__ o2,
    unsigned short* __restrict__ qh_o, unsigned short* __restrict__ ql_o)
{
    __shared__ unsigned char lds[32768];   // Ahi|Alo|Bhi|Blo, 8KB each
    const int tid = threadIdx.x;
    const int wave = tid >> 6, lane = tid & 63;
    const int bm = blockIdx.y, bn = blockIdx.x;

    const unsigned short* mysrc;
    if      (wave == 0) mysrc = Ahg + (size_t)bm * 32 * 4096;
    else if (wave == 1) mysrc = Alg + (size_t)bm * 32 * 4096;
    else if (wave == 2) mysrc = Bhg + (size_t)bn * 32 * 4096;
    else                mysrc = Blg + (size_t)bn * 32 * 4096;

    const f32x4 fzero = {0.f, 0.f, 0.f, 0.f};
    f32x4 acc[4][4];
    #pragma unroll
    for (int i = 0; i < 4; ++i)
        #pragma unroll
        for (int j = 0; j < 4; ++j) acc[i][j] = fzero;

    const int frag_off = ((lane >> 4) << 8) + ((lane & 15) << 4);  // = lane*16
    const int ag = (wave >> 1) * 4;
    const int bg = (wave & 1) * 4;

    for (int kt = 0; kt < 32; ++kt) {
        __syncthreads();
        const unsigned short* src = mysrc + kt * 4096;
        #pragma unroll
        for (int c = 0; c < 8; ++c) {
            const unsigned short* gsrc = src + (c << 9) + (lane << 3);
            __builtin_amdgcn_global_load_lds(
                (gptr_t)(uintptr_t)gsrc,
                (lptr_t)(uintptr_t)(&lds[(wave << 13) + (c << 10)]),
                16, 0, 0);
        }
        __syncthreads();

        short8 ah[4], al[4], bh[4], bl[4];
        #pragma unroll
        for (int i = 0; i < 4; ++i) {
            const int ao = (ag + i) * 1024 + frag_off;
            const int bo = (bg + i) * 1024 + frag_off;
            ah[i] = __builtin_bit_cast(short8, *(const uint4*)&lds[ao]);
            al[i] = __builtin_bit_cast(short8, *(const uint4*)&lds[8192 + ao]);
            bh[i] = __builtin_bit_cast(short8, *(const uint4*)&lds[16384 + bo]);
            bl[i] = __builtin_bit_cast(short8, *(const uint4*)&lds[24576 + bo]);
        }
        #pragma unroll
        for (int i = 0; i < 4; ++i)
            #pragma unroll
            for (int j = 0; j < 4; ++j) {
                acc[i][j] = __builtin_amdgcn_mfma_f32_16x16x32_bf16(ah[i], bh[j], acc[i][j], 0, 0, 0);
                acc[i][j] = __builtin_amdgcn_mfma_f32_16x16x32_bf16(ah[i], bl[j], acc[i][j], 0, 0, 0);
                acc[i][j] = __builtin_amdgcn_mfma_f32_16x16x32_bf16(al[i], bh[j], acc[i][j], 0, 0, 0);
            }
    }

    // epilogue: C/D layout col=lane&15, row=(lane>>4)*4+reg
    const int gm_base = bm * 128 + (wave >> 1) * 64 + ((lane >> 4) << 2);
    const int gn_base = bn * 128 + (wave & 1) * 64 + (lane & 15);
    #pragma unroll
    for (int j = 0; j < 4; ++j) {
        const int gn = gn_base + j * 16;
        const float bj = bias[gn];
        if (EPI == 0) {
            #pragma unroll
            for (int i = 0; i < 4; ++i)
                #pragma unroll
                for (int r = 0; r < 4; ++r)
                    o0[(size_t)(gm_base + i * 16 + r) * NXDIM + gn] = acc[i][j][r] + bj;
        } else {
            const int sec = gn >> 10;
            const int hh  = (gn >> 6) & 15;
            const int d   = gn & 63;
            #pragma unroll
            for (int i = 0; i < 4; ++i)
                #pragma unroll
                for (int r = 0; r < 4; ++r) {
                    const int gm = gm_base + i * 16 + r;
                    const int bq = gm >> 10, s = gm & 1023;
                    const size_t idx = (((size_t)bq * NHEAD + hh) * SEQ + s) * DHEAD + d;
                    const float val = acc[i][j][r] + bj;
                    if (sec == 1)      o1[idx] = val;
                    else if (sec == 2) o2[idx] = val;
                    else {
                        const float vq = val * 0.125f;          // fold 1/sqrt(D)
                        const unsigned short hq = f2bf(vq);
                        qh_o[idx] = hq;
                        ql_o[idx] = f2bf(vq - bf2f(hq));
                    }
                }
        }
    }
}

// ---------------------------------------------------------------------------
// MFMA flash attention. 4 waves/block, wave owns 16 q-rows of a 64-row tile.
// Q hi/lo in registers (pre-scaled); K/V staged to LDS as hi/lo bf16
// (V transposed), row-XOR-swizzled. S and PV are 3-term split-bf16 MFMAs.
// P routed through per-wave LDS as packed (hi|lo) uints.
// ---------------------------------------------------------------------------
__global__ __launch_bounds__(256, 3) void attn_kernel(
    const unsigned short* __restrict__ qh_g, const unsigned short* __restrict__ ql_g,
    const float* __restrict__ kbuf, const float* __restrict__ vbuf,
    unsigned short* __restrict__ ahi, unsigned short* __restrict__ alo)
{
    __shared__ unsigned char lds[49152];
    unsigned char* const Kh  = lds;              // [key][d] hi, swizzled slots
    unsigned char* const Kl  = lds + 8192;
    unsigned char* const Vth = lds + 16384;      // [d][key] hi (transposed)
    unsigned char* const Vtl = lds + 24576;

    const int tid  = threadIdx.x;
    const int wave = tid >> 6, lane = tid & 63;
    const int l15  = lane & 15, lg = lane >> 4;
    const int qt = 15 - (int)(blockIdx.x & 15);  // heavy q-tiles first
    const int bh = (int)(blockIdx.x >> 4);
    const int q0 = qt << 6;
    unsigned char* const Ps = lds + 32768 + (wave << 12);  // per-wave 4KB

    const float* kb = kbuf + (size_t)bh * SEQ * DHEAD;
    const float* vb = vbuf + (size_t)bh * SEQ * DHEAD;

    // Q A-fragments in registers: row=l15 (wave's 16-row group), k=lg*8+e
    short8 qhf[2], qlf[2];
    {
        const size_t qb0 = ((size_t)bh * SEQ + q0 + wave * 16 + l15) * DHEAD + lg * 8;
        qhf[0] = *(const short8*)(qh_g + qb0);
        qhf[1] = *(const short8*)(qh_g + qb0 + 32);
        qlf[0] = *(const short8*)(ql_g + qb0);
        qlf[1] = *(const short8*)(ql_g + qb0 + 32);
    }

    const int krow = tid >> 2, kdq = (tid & 3) << 4;  // K staging: row, d-base
    const int vrow = tid & 63, vkq = tid >> 6;        // V staging: Vt row(=d), key-quarter

    float4 kreg[4];
    float  vreg[16];

    auto load_tile = [&](int kb0) {
        #pragma unroll
        for (int c = 0; c < 4; ++c)
            kreg[c] = *(const float4*)&kb[(size_t)(kb0 + krow) * DHEAD + kdq + 4 * c];
        #pragma unroll
        for (int kk = 0; kk < 16; ++kk)
            vreg[kk] = vb[(size_t)(kb0 + vkq * 16 + kk) * DHEAD + vrow];
    };
    auto commit = [&]() {
        #pragma unroll
        for (int c = 0; c < 4; ++c) {
            const float4 f = kreg[c];
            const unsigned h01 = pk_hi_rtne(f.x, f.y);
            const unsigned h23 = pk_hi_rtne(f.z, f.w);
            const unsigned l01 = pk_hi_trunc(f.x - rtne_bf(f.x), f.y - rtne_bf(f.y));
            const unsigned l23 = pk_hi_trunc(f.z - rtne_bf(f.z), f.w - rtne_bf(f.w));
            const int slot = ((tid & 3) << 1) + (c >> 1);
            const int addr = krow * 128 + ((slot ^ (krow & 7)) << 4) + ((c & 1) << 3);
            *(uint2*)(Kh + addr) = make_uint2(h01, h23);
            *(uint2*)(Kl + addr) = make_uint2(l01, l23);
        }
        unsigned vhp[8], vlp[8];
        #pragma unroll
        for (int p = 0; p < 8; ++p) {
            const float a = vreg[2 * p], b2 = vreg[2 * p + 1];
            vhp[p] = pk_hi_trunc(a, b2);
            vlp[p] = pk_hi_trunc(a - trunc_bf(a), b2 - trunc_bf(b2));
        }
        const int vs0 = vkq << 1;
        const int vb0 = vrow * 128;
        const int vsw = vrow & 7;
        *(uint4*)(Vth + vb0 + (((vs0    ) ^ vsw) << 4)) = make_uint4(vhp[0], vhp[1], vhp[2], vhp[3]);
        *(uint4*)(Vth + vb0 + (((vs0 + 1) ^ vsw) << 4)) = make_uint4(vhp[4], vhp[5], vhp[6], vhp[7]);
        *(uint4*)(Vtl + vb0 + (((vs0    ) ^ vsw) << 4)) = make_uint4(vlp[0], vlp[1], vlp[2], vlp[3]);
        *(uint4*)(Vtl + vb0 + (((vs0 + 1) ^ vsw) << 4)) = make_uint4(vlp[4], vlp[5], vlp[6], vlp[7]);
    };

    load_tile(0);
    commit();

    float mprev[4], lsum[4];
    f32x4 oacc[4];
    #pragma unroll
    for (int r = 0; r < 4; ++r) { mprev[r] = -3.0e38f; lsum[r] = 0.f; }
    #pragma unroll
    for (int jd = 0; jd < 4; ++jd) oacc[jd] = (f32x4){0.f, 0.f, 0.f, 0.f};

    const int fsw = lg ^ (l15 & 7);   // frag slot swizzle (ks=0)

    for (int kt = 0; kt <= qt; ++kt) {
        __syncthreads();              // staged K/V visible
        if (kt < qt) load_tile((kt + 1) << 6);   // prefetch under compute

        // ---- scores: S = Q·K^T (3-term split)
        f32x4 sacc[4];
        #pragma unroll
        for (int j = 0; j < 4; ++j) sacc[j] = (f32x4){0.f, 0.f, 0.f, 0.f};
        #pragma unroll
        for (int ks = 0; ks < 2; ++ks) {
            #pragma unroll
            for (int j = 0; j < 4; ++j) {
                const int addr = ((j << 4) + l15) * 128 + ((fsw ^ (ks << 2)) << 4);
                const short8 khf = *(const short8*)(Kh + addr);
                const short8 klf = *(const short8*)(Kl + addr);
                sacc[j] = __builtin_amdgcn_mfma_f32_16x16x32_bf16(qhf[ks], khf, sacc[j], 0, 0, 0);
                sacc[j] = __builtin_amdgcn_mfma_f32_16x16x32_bf16(qhf[ks], klf, sacc[j], 0, 0, 0);
                sacc[j] = __builtin_amdgcn_mfma_f32_16x16x32_bf16(qlf[ks], khf, sacc[j], 0, 0, 0);
            }
        }

        // ---- online softmax (rows owned lane-locally: r + lg)
        const int k0 = kt << 6;
        const bool diag = (kt == qt);
        #pragma unroll
        for (int r = 0; r < 4; ++r) {
            const int qg = q0 + wave * 16 + lg * 4 + r;
            float mx = -3.0e38f;
            #pragma unroll
            for (int j = 0; j < 4; ++j) {
                float sv = sacc[j][r];
                if (diag && (k0 + (j << 4) + l15) > qg) sv = -1.0e9f;
                sacc[j][r] = sv;
                mx = fmaxf(mx, sv);
            }
            mx = fmaxf(mx, __shfl_xor(mx, 1));
            mx = fmaxf(mx, __shfl_xor(mx, 2));
            mx = fmaxf(mx, __shfl_xor(mx, 4));
            mx = fmaxf(mx, __shfl_xor(mx, 8));
            const float mnew = fmaxf(mprev[r], mx);
            const float corr = __expf(mprev[r] - mnew);
            float rsum = 0.f;
            #pragma unroll
            for (int j = 0; j < 4; ++j) {
                const float p = __expf(sacc[j][r] - mnew);
                sacc[j][r] = p;
                rsum += p;
            }
            rsum += __shfl_xor(rsum, 1);
            rsum += __shfl_xor(rsum, 2);
            rsum += __shfl_xor(rsum, 4);
            rsum += __shfl_xor(rsum, 8);
            lsum[r] = lsum[r] * corr + rsum;
            mprev[r] = mnew;
            #pragma unroll
            for (int jd = 0; jd < 4; ++jd) oacc[jd][r] *= corr;
        }

        // ---- P -> per-wave LDS as packed (hi16|lo16)
        #pragma unroll
        for (int j = 0; j < 4; ++j)
            #pragma unroll
            for (int r = 0; r < 4; ++r) {
                const float p = sacc[j][r];
                const unsigned up = __float_as_uint(p);
                const float plo = p - __uint_as_float(up & 0xFFFF0000u);
                const unsigned packed = (up & 0xFFFF0000u) | (__float_as_uint(plo) >> 16);
                const int qq = lg * 4 + r;
                const int kcol = (j << 4) + l15;
                const int addr = qq * 256 + (((kcol >> 2) ^ qq) << 4) + ((kcol & 3) << 2);
                *(unsigned*)(Ps + addr) = packed;
            }

        // ---- PV: O += P·V (3-term split)
        #pragma unroll
        for (int ks = 0; ks < 2; ++ks) {
            const int s0 = (ks << 3) + (lg << 1);
            const uint4 pk0 = *(const uint4*)(Ps + l15 * 256 + (((s0    ) ^ l15) << 4));
            const uint4 pk1 = *(const uint4*)(Ps + l15 * 256 + (((s0 + 1) ^ l15) << 4));
            uint4 uh, ul;
            uh.x = __builtin_amdgcn_perm(pk0.y, pk0.x, 0x07060302u);
            uh.y = __builtin_amdgcn_perm(pk0.w, pk0.z, 0x07060302u);
            uh.z = __builtin_amdgcn_perm(pk1.y, pk1.x, 0x07060302u);
            uh.w = __builtin_amdgcn_perm(pk1.w, pk1.z, 0x07060302u);
            ul.x = __builtin_amdgcn_perm(pk0.y, pk0.x, 0x05040100u);
            ul.y = __builtin_amdgcn_perm(pk0.w, pk0.z, 0x05040100u);
            ul.z = __builtin_amdgcn_perm(pk1.y, pk1.x, 0x05040100u);
            ul.w = __builtin_amdgcn_perm(pk1.w, pk1.z, 0x05040100u);
            const short8 phf = __builtin_bit_cast(short8, uh);
            const short8 plf = __builtin_bit_cast(short8, ul);
            #pragma unroll
            for (int jd = 0; jd < 4; ++jd) {
                const int vaddr = ((jd << 4) + l15) * 128 + ((fsw ^ (ks << 2)) << 4);
                const short8 vhf = *(const short8*)(Vth + vaddr);
                const short8 vlf = *(const short8*)(Vtl + vaddr);
                oacc[jd] = __builtin_amdgcn_mfma_f32_16x16x32_bf16(phf, vhf, oacc[jd], 0, 0, 0);
                oacc[jd] = __builtin_amdgcn_mfma_f32_16x16x32_bf16(phf, vlf, oacc[jd], 0, 0, 0);
                oacc[jd] = __builtin_amdgcn_mfma_f32_16x16x32_bf16(plf, vhf, oacc[jd], 0, 0, 0);
            }
        }

        __syncthreads();              // all LDS reads done
        if (kt < qt) commit();        // write next tile
    }

    // ---- epilogue: normalize, split hi/lo, write proj-A tiled layout
    const int hh = bh & 15, bq = bh >> 4;
    float inv[4];
    #pragma unroll
    for (int r = 0; r < 4; ++r) inv[r] = 1.0f / lsum[r];
    #pragma unroll
    for (int jd = 0; jd < 4; ++jd) {
        const int kcol = (hh << 6) + (jd << 4) + l15;
        const int ktile = kcol >> 5, khalf = (kcol & 31) >> 3, k7 = kcol & 7;
        #pragma unroll
        for (int r = 0; r < 4; ++r) {
            const int m = (bq << 10) + q0 + wave * 16 + lg * 4 + r;
            const float o = oacc[jd][r] * inv[r];
            const unsigned short hv = f2bf(o);
            const unsigned short lv = f2bf(o - bf2f(hv));
            const size_t off = ((size_t)((m >> 7) * 32 + ktile) << 12)
                             + (size_t)((((m & 127) >> 4) << 9) + (khalf << 7) + ((m & 15) << 3) + k7);
            ahi[off] = hv;
            alo[off] = lv;
        }
    }
}

extern "C" void kernel_launch(void* const* d_in, const int* in_sizes, int n_in,
                              void* d_out, int out_size, void* d_ws, size_t ws_size,
                              hipStream_t stream) {
    const float* x      = (const float*)d_in[0];
    // d_in[1] = causal mask — analytic, ignored
    const float* w_attn = (const float*)d_in[2];
    const float* b_attn = (const float*)d_in[3];
    const float* w_proj = (const float*)d_in[4];
    const float* b_proj = (const float*)d_in[5];

    float* out = (float*)d_out;
    float* kbuf = out + (size_t)BATCH * SEQ * NXDIM;            // present: k
    float* vbuf = kbuf + (size_t)BATCH * NHEAD * SEQ * DHEAD;   // present: v
    // q hi/lo live in the `a` region of d_out (16MB, dead until proj writes it)
    unsigned short* qh = (unsigned short*)out;                  // 8 MB
    unsigned short* ql = qh + (size_t)BATCH * NHEAD * SEQ * DHEAD;  // 8 MB

    unsigned char* ws = (unsigned char*)d_ws;                   // 32 MB used
    unsigned short* xh  = (unsigned short*)(ws);                // 8 MB
    unsigned short* xl  = (unsigned short*)(ws + (8u  << 20));  // 8 MB
    unsigned short* wah = (unsigned short*)(ws + (16u << 20));  // 6 MB
    unsigned short* wal = (unsigned short*)(ws + (22u << 20));  // 6 MB
    unsigned short* wph = (unsigned short*)(ws + (28u << 20));  // 2 MB
    unsigned short* wpl = (unsigned short*)(ws + (30u << 20));  // 2 MB
    unsigned short* ah  = xh;   // x-split dead after qkv gemm — reuse
    unsigned short* al  = xl;

    split_x_kernel<<<2048, 256, 0, stream>>>(x, xh, xl);
    split_w_kernel<<<1536, 256, 0, stream>>>(w_attn, wah, wal, QKVN);
    split_w_kernel<<<512,  256, 0, stream>>>(w_proj, wph, wpl, NXDIM);
    mfma_gemm_kernel<1><<<dim3(24, 32), 256, 0, stream>>>(
        xh, xl, wah, wal, b_attn, nullptr, kbuf, vbuf, qh, ql);
    attn_kernel<<<1024, 256, 0, stream>>>(qh, ql, kbuf, vbuf, ah, al);
    mfma_gemm_kernel<0><<<dim3(8, 32), 256, 0, stream>>>(
        ah, al, wph, wpl, b_proj, out, nullptr, nullptr, nullptr, nullptr);
}

// Round 7
// 273.450 us; speedup vs baseline: 1.9028x; 1.1705x over previous
//
#include <hip/hip_runtime.h>
#include <math.h>
#include <stdint.h>

#define BATCH 4
#define SEQ   1024
#define NXDIM 1024
#define NHEAD 16
#define DHEAD 64
#define QKVN  3072
#define MROWS 4096
#define KDIM  1024

typedef short short8 __attribute__((ext_vector_type(8)));   // 8 x bf16 bits
typedef float f32x4  __attribute__((ext_vector_type(4)));

typedef const __attribute__((address_space(1))) unsigned int* gptr_t;
typedef __attribute__((address_space(3))) unsigned int* lptr_t;

__device__ __forceinline__ unsigned short f2bf(float f) {
    unsigned int u = __float_as_uint(f);
    u += 0x7FFF + ((u >> 16) & 1);          // round-to-nearest-even
    return (unsigned short)(u >> 16);
}
__device__ __forceinline__ float bf2f(unsigned short h) {
    return __uint_as_float(((unsigned int)h) << 16);
}
// pack two floats' RTNE-bf16 into one uint (a in low half)
__device__ __forceinline__ unsigned pk_hi_rtne(float a, float b) {
    unsigned ua = __float_as_uint(a), ub = __float_as_uint(b);
    ua += 0x7FFF + ((ua >> 16) & 1);
    ub += 0x7FFF + ((ub >> 16) & 1);
    return __builtin_amdgcn_perm(ub, ua, 0x07060302u);
}
// pack two floats' trunc-bf16 into one uint
__device__ __forceinline__ unsigned pk_hi_trunc(float a, float b) {
    return __builtin_amdgcn_perm(__float_as_uint(b), __float_as_uint(a), 0x07060302u);
}
__device__ __forceinline__ float trunc_bf(float a) {
    return __uint_as_float(__float_as_uint(a) & 0xFFFF0000u);
}
__device__ __forceinline__ float rtne_bf(float a) {
    unsigned u = __float_as_uint(a);
    u += 0x7FFF + ((u >> 16) & 1);
    return __uint_as_float(u & 0xFFFF0000u);
}

// ---------------------------------------------------------------------------
// Split x (M=4096, K=1024, row-major) into hi/lo bf16 in A-tiled layout:
// [mt:32][kt:32][g:8][khalf:4][r16:16][k8:8]  (tile = 4096 elems = 8 KB)
// ---------------------------------------------------------------------------
__global__ __launch_bounds__(256) void split_x_kernel(
    const float* __restrict__ x, unsigned short* __restrict__ xh,
    unsigned short* __restrict__ xl)
{
    const int t = blockIdx.x * 256 + threadIdx.x;       // 524288 threads
    const int tile = t >> 9, u = t & 511;
    const int mt = tile >> 5, kt = tile & 31;
    const int g = u >> 6, khalf = (u >> 4) & 3, r16 = u & 15;
    const int m = mt * 128 + g * 16 + r16;
    const int k = kt * 32 + khalf * 8;
    const float4 v0 = *(const float4*)&x[(size_t)m * KDIM + k];
    const float4 v1 = *(const float4*)&x[(size_t)m * KDIM + k + 4];
    const float vv[8] = {v0.x, v0.y, v0.z, v0.w, v1.x, v1.y, v1.z, v1.w};
    unsigned short h[8], l[8];
    #pragma unroll
    for (int e = 0; e < 8; ++e) {
        h[e] = f2bf(vv[e]);
        l[e] = f2bf(vv[e] - bf2f(h[e]));
    }
    uint4 ph, pl;
    ph.x = (unsigned)h[0] | ((unsigned)h[1] << 16);
    ph.y = (unsigned)h[2] | ((unsigned)h[3] << 16);
    ph.z = (unsigned)h[4] | ((unsigned)h[5] << 16);
    ph.w = (unsigned)h[6] | ((unsigned)h[7] << 16);
    pl.x = (unsigned)l[0] | ((unsigned)l[1] << 16);
    pl.y = (unsigned)l[2] | ((unsigned)l[3] << 16);
    pl.z = (unsigned)l[4] | ((unsigned)l[5] << 16);
    pl.w = (unsigned)l[6] | ((unsigned)l[7] << 16);
    *(uint4*)&xh[(size_t)t * 8] = ph;
    *(uint4*)&xl[(size_t)t * 8] = pl;
}

// ---------------------------------------------------------------------------
// Split w[K=1024][N] into hi/lo bf16 in B-tiled layout:
// [nt:N/128][kt:32][gn:8][khalf:4][c16:16][k8:8]
// ---------------------------------------------------------------------------
__global__ __launch_bounds__(256) void split_w_kernel(
    const float* __restrict__ w, unsigned short* __restrict__ wh,
    unsigned short* __restrict__ wl, int N)
{
    const int t = blockIdx.x * 256 + threadIdx.x;       // N*128 threads
    const int tile = t >> 9, u = t & 511;
    const int nt = tile >> 5, kt = tile & 31;
    const int gn = u >> 6, khalf = (u >> 4) & 3, c16 = u & 15;
    const int n = nt * 128 + gn * 16 + c16;
    const int k0 = kt * 32 + khalf * 8;
    unsigned short h[8], l[8];
    #pragma unroll
    for (int e = 0; e < 8; ++e) {
        const float v = w[(size_t)(k0 + e) * N + n];
        h[e] = f2bf(v);
        l[e] = f2bf(v - bf2f(h[e]));
    }
    uint4 ph, pl;
    ph.x = (unsigned)h[0] | ((unsigned)h[1] << 16);
    ph.y = (unsigned)h[2] | ((unsigned)h[3] << 16);
    ph.z = (unsigned)h[4] | ((unsigned)h[5] << 16);
    ph.w = (unsigned)h[6] | ((unsigned)h[7] << 16);
    pl.x = (unsigned)l[0] | ((unsigned)l[1] << 16);
    pl.y = (unsigned)l[2] | ((unsigned)l[3] << 16);
    pl.z = (unsigned)l[4] | ((unsigned)l[5] << 16);
    pl.w = (unsigned)l[6] | ((unsigned)l[7] << 16);
    *(uint4*)&wh[(size_t)t * 8] = ph;
    *(uint4*)&wl[(size_t)t * 8] = pl;
}

// ---------------------------------------------------------------------------
// Split-bf16 MFMA GEMM, m97 structure: 128x128 tile, BK=32, 4 waves.
// D = Ahi*Bhi + Ahi*Blo + Alo*Bhi  (fp32 accumulate) + bias.
// EPI 0: plain C[m][1024]
// EPI 1: qkv scatter — q as hi/lo bf16 pre-scaled by 0.125*log2(e)
//        (exp2-domain logits), k/v fp32 head-major.
// ---------------------------------------------------------------------------
template<int EPI>
__global__ __launch_bounds__(256, 2) void mfma_gemm_kernel(
    const unsigned short* __restrict__ Ahg, const unsigned short* __restrict__ Alg,
    const unsigned short* __restrict__ Bhg, const unsigned short* __restrict__ Blg,
    const float* __restrict__ bias,
    float* __restrict__ o0, float* __restrict__ o1, float* __restrict__ o2,
    unsigned short* __restrict__ qh_o, unsigned short* __restrict__ ql_o)
{
    __shared__ unsigned char lds[32768];   // Ahi|Alo|Bhi|Blo, 8KB each
    const int tid = threadIdx.x;
    const int wave = tid >> 6, lane = tid & 63;
    const int bm = blockIdx.y, bn = blockIdx.x;

    const unsigned short* mysrc;
    if      (wave == 0) mysrc = Ahg + (size_t)bm * 32 * 4096;
    else if (wave == 1) mysrc = Alg + (size_t)bm * 32 * 4096;
    else if (wave == 2) mysrc = Bhg + (size_t)bn * 32 * 4096;
    else                mysrc = Blg + (size_t)bn * 32 * 4096;

    const f32x4 fzero = {0.f, 0.f, 0.f, 0.f};
    f32x4 acc[4][4];
    #pragma unroll
    for (int i = 0; i < 4; ++i)
        #pragma unroll
        for (int j = 0; j < 4; ++j) acc[i][j] = fzero;

    const int frag_off = ((lane >> 4) << 8) + ((lane & 15) << 4);  // = lane*16
    const int ag = (wave >> 1) * 4;
    const int bg = (wave & 1) * 4;

    for (int kt = 0; kt < 32; ++kt) {
        __syncthreads();
        const unsigned short* src = mysrc + kt * 4096;
        #pragma unroll
        for (int c = 0; c < 8; ++c) {
            const unsigned short* gsrc = src + (c << 9) + (lane << 3);
            __builtin_amdgcn_global_load_lds(
                (gptr_t)(uintptr_t)gsrc,
                (lptr_t)(uintptr_t)(&lds[(wave << 13) + (c << 10)]),
                16, 0, 0);
        }
        __syncthreads();

        short8 ah[4], al[4], bh[4], bl[4];
        #pragma unroll
        for (int i = 0; i < 4; ++i) {
            const int ao = (ag + i) * 1024 + frag_off;
            const int bo = (bg + i) * 1024 + frag_off;
            ah[i] = __builtin_bit_cast(short8, *(const uint4*)&lds[ao]);
            al[i] = __builtin_bit_cast(short8, *(const uint4*)&lds[8192 + ao]);
            bh[i] = __builtin_bit_cast(short8, *(const uint4*)&lds[16384 + bo]);
            bl[i] = __builtin_bit_cast(short8, *(const uint4*)&lds[24576 + bo]);
        }
        #pragma unroll
        for (int i = 0; i < 4; ++i)
            #pragma unroll
            for (int j = 0; j < 4; ++j) {
                acc[i][j] = __builtin_amdgcn_mfma_f32_16x16x32_bf16(ah[i], bh[j], acc[i][j], 0, 0, 0);
                acc[i][j] = __builtin_amdgcn_mfma_f32_16x16x32_bf16(ah[i], bl[j], acc[i][j], 0, 0, 0);
                acc[i][j] = __builtin_amdgcn_mfma_f32_16x16x32_bf16(al[i], bh[j], acc[i][j], 0, 0, 0);
            }
    }

    // epilogue: C/D layout col=lane&15, row=(lane>>4)*4+reg
    const int gm_base = bm * 128 + (wave >> 1) * 64 + ((lane >> 4) << 2);
    const int gn_base = bn * 128 + (wave & 1) * 64 + (lane & 15);
    #pragma unroll
    for (int j = 0; j < 4; ++j) {
        const int gn = gn_base + j * 16;
        const float bj = bias[gn];
        if (EPI == 0) {
            #pragma unroll
            for (int i = 0; i < 4; ++i)
                #pragma unroll
                for (int r = 0; r < 4; ++r)
                    o0[(size_t)(gm_base + i * 16 + r) * NXDIM + gn] = acc[i][j][r] + bj;
        } else {
            const int sec = gn >> 10;
            const int hh  = (gn >> 6) & 15;
            const int d   = gn & 63;
            #pragma unroll
            for (int i = 0; i < 4; ++i)
                #pragma unroll
                for (int r = 0; r < 4; ++r) {
                    const int gm = gm_base + i * 16 + r;
                    const int bq = gm >> 10, s = gm & 1023;
                    const size_t idx = (((size_t)bq * NHEAD + hh) * SEQ + s) * DHEAD + d;
                    const float val = acc[i][j][r] + bj;
                    if (sec == 1)      o1[idx] = val;
                    else if (sec == 2) o2[idx] = val;
                    else {
                        // fold 1/sqrt(D) * log2(e): exp2-domain logits
                        const float vq = val * 0.18033688f;
                        const unsigned short hq = f2bf(vq);
                        qh_o[idx] = hq;
                        ql_o[idx] = f2bf(vq - bf2f(hq));
                    }
                }
        }
    }
}

// ---------------------------------------------------------------------------
// MFMA flash attention, causal-balanced: block handles q-tile pair
// (pp, 15-pp) sequentially -> uniform 17 k-tiles/block, grid 512.
// exp2-domain softmax (log2e folded into Q), lsum via ones-MFMA,
// defer-max rescale (THR=8), setprio around MFMA clusters.
// ---------------------------------------------------------------------------
__global__ __launch_bounds__(256, 3) void attn_kernel(
    const unsigned short* __restrict__ qh_g, const unsigned short* __restrict__ ql_g,
    const float* __restrict__ kbuf, const float* __restrict__ vbuf,
    unsigned short* __restrict__ ahi, unsigned short* __restrict__ alo)
{
    __shared__ unsigned char lds[49152];
    unsigned char* const Kh  = lds;              // [key][d] hi, swizzled slots
    unsigned char* const Kl  = lds + 8192;
    unsigned char* const Vth = lds + 16384;      // [d][key] hi (transposed)
    unsigned char* const Vtl = lds + 24576;

    const int tid  = threadIdx.x;
    const int wave = tid >> 6, lane = tid & 63;
    const int l15  = lane & 15, lg = lane >> 4;
    const int pp = (int)(blockIdx.x & 7);        // pair index
    const int bh = (int)(blockIdx.x >> 3);
    unsigned char* const Ps = lds + 32768 + (wave << 12);  // per-wave 4KB

    const float* kb = kbuf + (size_t)bh * SEQ * DHEAD;
    const float* vb = vbuf + (size_t)bh * SEQ * DHEAD;

    const int krow = tid >> 2, kdq = (tid & 3) << 4;  // K staging: row, d-base
    const int vrow = tid & 63, vkq = tid >> 6;        // V staging: Vt row(=d), key-quarter

    float4 kreg[4];
    float  vreg[16];

    auto load_tile = [&](int kb0) {
        #pragma unroll
        for (int c = 0; c < 4; ++c)
            kreg[c] = *(const float4*)&kb[(size_t)(kb0 + krow) * DHEAD + kdq + 4 * c];
        #pragma unroll
        for (int kk = 0; kk < 16; ++kk)
            vreg[kk] = vb[(size_t)(kb0 + vkq * 16 + kk) * DHEAD + vrow];
    };
    auto commit = [&]() {
        #pragma unroll
        for (int c = 0; c < 4; ++c) {
            const float4 f = kreg[c];
            const unsigned h01 = pk_hi_rtne(f.x, f.y);
            const unsigned h23 = pk_hi_rtne(f.z, f.w);
            const unsigned l01 = pk_hi_trunc(f.x - rtne_bf(f.x), f.y - rtne_bf(f.y));
            const unsigned l23 = pk_hi_trunc(f.z - rtne_bf(f.z), f.w - rtne_bf(f.w));
            const int slot = ((tid & 3) << 1) + (c >> 1);
            const int addr = krow * 128 + ((slot ^ (krow & 7)) << 4) + ((c & 1) << 3);
            *(uint2*)(Kh + addr) = make_uint2(h01, h23);
            *(uint2*)(Kl + addr) = make_uint2(l01, l23);
        }
        unsigned vhp[8], vlp[8];
        #pragma unroll
        for (int p = 0; p < 8; ++p) {
            const float a = vreg[2 * p], b2 = vreg[2 * p + 1];
            vhp[p] = pk_hi_trunc(a, b2);
            vlp[p] = pk_hi_trunc(a - trunc_bf(a), b2 - trunc_bf(b2));
        }
        const int vs0 = vkq << 1;
        const int vb0 = vrow * 128;
        const int vsw = vrow & 7;
        *(uint4*)(Vth + vb0 + (((vs0    ) ^ vsw) << 4)) = make_uint4(vhp[0], vhp[1], vhp[2], vhp[3]);
        *(uint4*)(Vth + vb0 + (((vs0 + 1) ^ vsw) << 4)) = make_uint4(vhp[4], vhp[5], vhp[6], vhp[7]);
        *(uint4*)(Vtl + vb0 + (((vs0    ) ^ vsw) << 4)) = make_uint4(vlp[0], vlp[1], vlp[2], vlp[3]);
        *(uint4*)(Vtl + vb0 + (((vs0 + 1) ^ vsw) << 4)) = make_uint4(vlp[4], vlp[5], vlp[6], vlp[7]);
    };

    const int fsw = lg ^ (l15 & 7);   // frag slot swizzle (ks=0)
    const int hh = bh & 15, bq = bh >> 4;

    short8 vone;
    #pragma unroll
    for (int e = 0; e < 8; ++e) vone[e] = (short)0x3F80;   // bf16 1.0

    auto process = [&](int q0, int nt, bool has_next) {
        // Q A-fragments in registers: row=l15, k=lg*8+e (pre-scaled, exp2 dom)
        short8 qhf[2], qlf[2];
        {
            const size_t qb0 = ((size_t)bh * SEQ + q0 + wave * 16 + l15) * DHEAD + lg * 8;
            qhf[0] = *(const short8*)(qh_g + qb0);
            qhf[1] = *(const short8*)(qh_g + qb0 + 32);
            qlf[0] = *(const short8*)(ql_g + qb0);
            qlf[1] = *(const short8*)(ql_g + qb0 + 32);
        }
        float mprev[4];
        f32x4 lacc = (f32x4){0.f, 0.f, 0.f, 0.f};
        f32x4 oacc[4];
        #pragma unroll
        for (int r = 0; r < 4; ++r) mprev[r] = -3.0e38f;
        #pragma unroll
        for (int jd = 0; jd < 4; ++jd) oacc[jd] = (f32x4){0.f, 0.f, 0.f, 0.f};

        for (int kt = 0; kt < nt; ++kt) {
            __syncthreads();              // staged K/V visible
            const bool pf = (kt + 1 < nt) || has_next;
            if (pf) load_tile((kt + 1 < nt) ? (kt + 1) << 6 : 0);

            // ---- scores: S = Q·K^T (3-term split)
            f32x4 sacc[4];
            #pragma unroll
            for (int j = 0; j < 4; ++j) sacc[j] = (f32x4){0.f, 0.f, 0.f, 0.f};
            __builtin_amdgcn_s_setprio(1);
            #pragma unroll
            for (int ks = 0; ks < 2; ++ks) {
                #pragma unroll
                for (int j = 0; j < 4; ++j) {
                    const int addr = ((j << 4) + l15) * 128 + ((fsw ^ (ks << 2)) << 4);
                    const short8 khf = *(const short8*)(Kh + addr);
                    const short8 klf = *(const short8*)(Kl + addr);
                    sacc[j] = __builtin_amdgcn_mfma_f32_16x16x32_bf16(qhf[ks], khf, sacc[j], 0, 0, 0);
                    sacc[j] = __builtin_amdgcn_mfma_f32_16x16x32_bf16(qhf[ks], klf, sacc[j], 0, 0, 0);
                    sacc[j] = __builtin_amdgcn_mfma_f32_16x16x32_bf16(qlf[ks], khf, sacc[j], 0, 0, 0);
                }
            }
            __builtin_amdgcn_s_setprio(0);

            // ---- masked row-max (rows owned lane-locally: lg*4+r)
            const int k0 = kt << 6;
            const bool diag = (k0 == q0);
            float mx[4];
            #pragma unroll
            for (int r = 0; r < 4; ++r) {
                const int qg = q0 + wave * 16 + lg * 4 + r;
                float m_ = -3.0e38f;
                #pragma unroll
                for (int j = 0; j < 4; ++j) {
                    float sv = sacc[j][r];
                    if (diag && (k0 + (j << 4) + l15) > qg) sv = -1.0e9f;
                    sacc[j][r] = sv;
                    m_ = fmaxf(m_, sv);
                }
                m_ = fmaxf(m_, __shfl_xor(m_, 1));
                m_ = fmaxf(m_, __shfl_xor(m_, 2));
                m_ = fmaxf(m_, __shfl_xor(m_, 4));
                m_ = fmaxf(m_, __shfl_xor(m_, 8));
                mx[r] = m_;
            }

            // ---- defer-max: rescale only when some row grew past THR=8
            bool need = false;
            #pragma unroll
            for (int r = 0; r < 4; ++r) need |= (mx[r] > mprev[r] + 8.0f);
            if (__any(need)) {
                #pragma unroll
                for (int r = 0; r < 4; ++r) {
                    const float mnew = fmaxf(mprev[r], mx[r]);
                    const float corr = exp2f(mprev[r] - mnew);
                    lacc[r] *= corr;
                    #pragma unroll
                    for (int jd = 0; jd < 4; ++jd) oacc[jd][r] *= corr;
                    mprev[r] = mnew;
                }
            }

            // ---- P = exp2(S - m), packed (hi16|lo16) -> per-wave LDS
            #pragma unroll
            for (int j = 0; j < 4; ++j)
                #pragma unroll
                for (int r = 0; r < 4; ++r) {
                    const float p = exp2f(sacc[j][r] - mprev[r]);
                    const unsigned up = __float_as_uint(p);
                    const float plo = p - __uint_as_float(up & 0xFFFF0000u);
                    const unsigned packed = (up & 0xFFFF0000u) | (__float_as_uint(plo) >> 16);
                    const int qq = lg * 4 + r;
                    const int kcol = (j << 4) + l15;
                    const int addr = qq * 256 + (((kcol >> 2) ^ qq) << 4) + ((kcol & 3) << 2);
                    *(unsigned*)(Ps + addr) = packed;
                }

            // ---- PV: O += P·V (3-term split); lsum via ones-MFMA
            __builtin_amdgcn_s_setprio(1);
            #pragma unroll
            for (int ks = 0; ks < 2; ++ks) {
                const int s0 = (ks << 3) + (lg << 1);
                const uint4 pk0 = *(const uint4*)(Ps + l15 * 256 + (((s0    ) ^ l15) << 4));
                const uint4 pk1 = *(const uint4*)(Ps + l15 * 256 + (((s0 + 1) ^ l15) << 4));
                uint4 uh, ul;
                uh.x = __builtin_amdgcn_perm(pk0.y, pk0.x, 0x07060302u);
                uh.y = __builtin_amdgcn_perm(pk0.w, pk0.z, 0x07060302u);
                uh.z = __builtin_amdgcn_perm(pk1.y, pk1.x, 0x07060302u);
                uh.w = __builtin_amdgcn_perm(pk1.w, pk1.z, 0x07060302u);
                ul.x = __builtin_amdgcn_perm(pk0.y, pk0.x, 0x05040100u);
                ul.y = __builtin_amdgcn_perm(pk0.w, pk0.z, 0x05040100u);
                ul.z = __builtin_amdgcn_perm(pk1.y, pk1.x, 0x05040100u);
                ul.w = __builtin_amdgcn_perm(pk1.w, pk1.z, 0x05040100u);
                const short8 phf = __builtin_bit_cast(short8, uh);
                const short8 plf = __builtin_bit_cast(short8, ul);
                lacc = __builtin_amdgcn_mfma_f32_16x16x32_bf16(phf, vone, lacc, 0, 0, 0);
                lacc = __builtin_amdgcn_mfma_f32_16x16x32_bf16(plf, vone, lacc, 0, 0, 0);
                #pragma unroll
                for (int jd = 0; jd < 4; ++jd) {
                    const int vaddr = ((jd << 4) + l15) * 128 + ((fsw ^ (ks << 2)) << 4);
                    const short8 vhf = *(const short8*)(Vth + vaddr);
                    const short8 vlf = *(const short8*)(Vtl + vaddr);
                    oacc[jd] = __builtin_amdgcn_mfma_f32_16x16x32_bf16(phf, vhf, oacc[jd], 0, 0, 0);
                    oacc[jd] = __builtin_amdgcn_mfma_f32_16x16x32_bf16(phf, vlf, oacc[jd], 0, 0, 0);
                    oacc[jd] = __builtin_amdgcn_mfma_f32_16x16x32_bf16(plf, vhf, oacc[jd], 0, 0, 0);
                }
            }
            __builtin_amdgcn_s_setprio(0);

            __syncthreads();              // all LDS reads done
            if (pf) commit();             // write next tile (or pass-B tile 0)
        }

        // ---- epilogue: normalize, split hi/lo, write proj-A tiled layout
        float inv[4];
        #pragma unroll
        for (int r = 0; r < 4; ++r) inv[r] = 1.0f / lacc[r];
        #pragma unroll
        for (int jd = 0; jd < 4; ++jd) {
            const int kcol = (hh << 6) + (jd << 4) + l15;
            const int ktile = kcol >> 5, khalf = (kcol & 31) >> 3, k7 = kcol & 7;
            #pragma unroll
            for (int r = 0; r < 4; ++r) {
                const int m = (bq << 10) + q0 + wave * 16 + lg * 4 + r;
                const float o = oacc[jd][r] * inv[r];
                const unsigned short hv = f2bf(o);
                const unsigned short lv = f2bf(o - bf2f(hv));
                const size_t off = ((size_t)((m >> 7) * 32 + ktile) << 12)
                                 + (size_t)((((m & 127) >> 4) << 9) + (khalf << 7) + ((m & 15) << 3) + k7);
                ahi[off] = hv;
                alo[off] = lv;
            }
        }
    };

    load_tile(0);
    commit();
    process(pp << 6, pp + 1, true);              // small pass: tiles 0..pp
    process((15 - pp) << 6, 16 - pp, false);     // big pass:   tiles 0..15-pp
}

extern "C" void kernel_launch(void* const* d_in, const int* in_sizes, int n_in,
                              void* d_out, int out_size, void* d_ws, size_t ws_size,
                              hipStream_t stream) {
    const float* x      = (const float*)d_in[0];
    // d_in[1] = causal mask — analytic, ignored
    const float* w_attn = (const float*)d_in[2];
    const float* b_attn = (const float*)d_in[3];
    const float* w_proj = (const float*)d_in[4];
    const float* b_proj = (const float*)d_in[5];

    float* out = (float*)d_out;
    float* kbuf = out + (size_t)BATCH * SEQ * NXDIM;            // present: k
    float* vbuf = kbuf + (size_t)BATCH * NHEAD * SEQ * DHEAD;   // present: v
    // q hi/lo live in the `a` region of d_out (16MB, dead until proj writes it)
    unsigned short* qh = (unsigned short*)out;                  // 8 MB
    unsigned short* ql = qh + (size_t)BATCH * NHEAD * SEQ * DHEAD;  // 8 MB

    unsigned char* ws = (unsigned char*)d_ws;                   // 32 MB used
    unsigned short* xh  = (unsigned short*)(ws);                // 8 MB
    unsigned short* xl  = (unsigned short*)(ws + (8u  << 20));  // 8 MB
    unsigned short* wah = (unsigned short*)(ws + (16u << 20));  // 6 MB
    unsigned short* wal = (unsigned short*)(ws + (22u << 20));  // 6 MB
    unsigned short* wph = (unsigned short*)(ws + (28u << 20));  // 2 MB
    unsigned short* wpl = (unsigned short*)(ws + (30u << 20));  // 2 MB
    unsigned short* ah  = xh;   // x-split dead after qkv gemm — reuse
    unsigned short* al  = xl;

    split_x_kernel<<<2048, 256, 0, stream>>>(x, xh, xl);
    split_w_kernel<<<1536, 256, 0, stream>>>(w_attn, wah, wal, QKVN);
    split_w_kernel<<<512,  256, 0, stream>>>(w_proj, wpl == nullptr ? nullptr : wph, wpl, NXDIM);
    mfma_gemm_kernel<1><<<dim3(24, 32), 256, 0, stream>>>(
        xh, xl, wah, wal, b_attn, nullptr, kbuf, vbuf, qh, ql);
    attn_kernel<<<512, 256, 0, stream>>>(qh, ql, kbuf, vbuf, ah, al);
    mfma_gemm_kernel<0><<<dim3(8, 32), 256, 0, stream>>>(
        ah, al, wph, wpl, b_proj, out, nullptr, nullptr, nullptr, nullptr);
}

// Round 8
// 262.047 us; speedup vs baseline: 1.9856x; 1.0435x over previous
//
#include <hip/hip_runtime.h>
#include <math.h>
#include <stdint.h>

#define BATCH 4
#define SEQ   1024
#define NXDIM 1024
#define NHEAD 16
#define DHEAD 64
#define QKVN  3072
#define MROWS 4096
#define KDIM  1024

typedef short short8 __attribute__((ext_vector_type(8)));   // 8 x bf16 bits
typedef float f32x4  __attribute__((ext_vector_type(4)));

typedef const __attribute__((address_space(1))) unsigned int* gptr_t;
typedef __attribute__((address_space(3))) unsigned int* lptr_t;

__device__ __forceinline__ unsigned short f2bf(float f) {
    unsigned int u = __float_as_uint(f);
    u += 0x7FFF + ((u >> 16) & 1);          // round-to-nearest-even
    return (unsigned short)(u >> 16);
}
__device__ __forceinline__ float bf2f(unsigned short h) {
    return __uint_as_float(((unsigned int)h) << 16);
}
// pack two floats' RTNE-bf16 into one uint (a in low half)
__device__ __forceinline__ unsigned pk_hi_rtne(float a, float b) {
    unsigned ua = __float_as_uint(a), ub = __float_as_uint(b);
    ua += 0x7FFF + ((ua >> 16) & 1);
    ub += 0x7FFF + ((ub >> 16) & 1);
    return __builtin_amdgcn_perm(ub, ua, 0x07060302u);
}
// pack two floats' trunc-bf16 into one uint
__device__ __forceinline__ unsigned pk_hi_trunc(float a, float b) {
    return __builtin_amdgcn_perm(__float_as_uint(b), __float_as_uint(a), 0x07060302u);
}
__device__ __forceinline__ float trunc_bf(float a) {
    return __uint_as_float(__float_as_uint(a) & 0xFFFF0000u);
}
__device__ __forceinline__ float rtne_bf(float a) {
    unsigned u = __float_as_uint(a);
    u += 0x7FFF + ((u >> 16) & 1);
    return __uint_as_float(u & 0xFFFF0000u);
}

// ---------------------------------------------------------------------------
// Fused splitter: one launch produces all hi/lo bf16 tiled operands.
//  blocks [0,2048):    x  -> A-tiled  [mt:32][kt:32][g:8][khalf:4][r16:16][k8:8]
//  blocks [2048,3584): w_attn -> B-tiled [nt:24][kt:32][gn:8][khalf:4][c16:16][k8:8]
//  blocks [3584,4096): w_proj -> B-tiled [nt:8][...]
// ---------------------------------------------------------------------------
__device__ __forceinline__ void split_store8(
    const float* vv, unsigned short* dh, unsigned short* dl, size_t t)
{
    unsigned short h[8], l[8];
    #pragma unroll
    for (int e = 0; e < 8; ++e) {
        h[e] = f2bf(vv[e]);
        l[e] = f2bf(vv[e] - bf2f(h[e]));
    }
    uint4 ph, pl;
    ph.x = (unsigned)h[0] | ((unsigned)h[1] << 16);
    ph.y = (unsigned)h[2] | ((unsigned)h[3] << 16);
    ph.z = (unsigned)h[4] | ((unsigned)h[5] << 16);
    ph.w = (unsigned)h[6] | ((unsigned)h[7] << 16);
    pl.x = (unsigned)l[0] | ((unsigned)l[1] << 16);
    pl.y = (unsigned)l[2] | ((unsigned)l[3] << 16);
    pl.z = (unsigned)l[4] | ((unsigned)l[5] << 16);
    pl.w = (unsigned)l[6] | ((unsigned)l[7] << 16);
    *(uint4*)&dh[t * 8] = ph;
    *(uint4*)&dl[t * 8] = pl;
}

__global__ __launch_bounds__(256) void split_all_kernel(
    const float* __restrict__ x, const float* __restrict__ w_attn,
    const float* __restrict__ w_proj,
    unsigned short* __restrict__ xh, unsigned short* __restrict__ xl,
    unsigned short* __restrict__ wah, unsigned short* __restrict__ wal,
    unsigned short* __restrict__ wph, unsigned short* __restrict__ wpl)
{
    const int blk = blockIdx.x;
    if (blk < 2048) {
        const int t = blk * 256 + threadIdx.x;
        const int tile = t >> 9, u = t & 511;
        const int mt = tile >> 5, kt = tile & 31;
        const int g = u >> 6, khalf = (u >> 4) & 3, r16 = u & 15;
        const int m = mt * 128 + g * 16 + r16;
        const int k = kt * 32 + khalf * 8;
        const float4 v0 = *(const float4*)&x[(size_t)m * KDIM + k];
        const float4 v1 = *(const float4*)&x[(size_t)m * KDIM + k + 4];
        const float vv[8] = {v0.x, v0.y, v0.z, v0.w, v1.x, v1.y, v1.z, v1.w};
        split_store8(vv, xh, xl, (size_t)t);
    } else {
        const float* w;
        unsigned short *dh, *dl;
        int t, N;
        if (blk < 3584) { w = w_attn; dh = wah; dl = wal; N = QKVN;  t = (blk - 2048) * 256 + threadIdx.x; }
        else            { w = w_proj; dh = wph; dl = wpl; N = NXDIM; t = (blk - 3584) * 256 + threadIdx.x; }
        const int tile = t >> 9, u = t & 511;
        const int nt = tile >> 5, kt = tile & 31;
        const int gn = u >> 6, khalf = (u >> 4) & 3, c16 = u & 15;
        const int n = nt * 128 + gn * 16 + c16;
        const int k0 = kt * 32 + khalf * 8;
        float vv[8];
        #pragma unroll
        for (int e = 0; e < 8; ++e) vv[e] = w[(size_t)(k0 + e) * N + n];
        split_store8(vv, dh, dl, (size_t)t);
    }
}

// ---------------------------------------------------------------------------
// Split-bf16 MFMA GEMM, 128x128 tile, BK=32, 4 waves.
// R8: double-buffered LDS (2x32KB) with issue-early global_load_lds —
// next K-step's loads are in flight during the current step's 48 MFMAs;
// the single __syncthreads()'s implicit vmcnt(0) is covered by compute.
// D = Ahi*Bhi + Ahi*Blo + Alo*Bhi  (fp32 accumulate) + bias.
// EPI 0: plain C[m][1024]
// EPI 1: qkv scatter — q as hi/lo bf16 pre-scaled by 0.125*log2(e)
//        (exp2-domain logits), k/v fp32 head-major.
// ---------------------------------------------------------------------------
template<int EPI>
__global__ __launch_bounds__(256, 2) void mfma_gemm_kernel(
    const unsigned short* __restrict__ Ahg, const unsigned short* __restrict__ Alg,
    const unsigned short* __restrict__ Bhg, const unsigned short* __restrict__ Blg,
    const float* __restrict__ bias,
    float* __restrict__ o0, float* __restrict__ o1, float* __restrict__ o2,
    unsigned short* __restrict__ qh_o, unsigned short* __restrict__ ql_o)
{
    __shared__ unsigned char lds[65536];   // 2 x (Ahi|Alo|Bhi|Blo, 8KB each)
    const int tid = threadIdx.x;
    const int wave = tid >> 6, lane = tid & 63;
    const int bm = blockIdx.y, bn = blockIdx.x;

    // each wave stages exactly one of the four 8KB quarters per K-step
    const unsigned short* mysrc;
    if      (wave == 0) mysrc = Ahg + (size_t)bm * 32 * 4096;
    else if (wave == 1) mysrc = Alg + (size_t)bm * 32 * 4096;
    else if (wave == 2) mysrc = Bhg + (size_t)bn * 32 * 4096;
    else                mysrc = Blg + (size_t)bn * 32 * 4096;

    const f32x4 fzero = {0.f, 0.f, 0.f, 0.f};
    f32x4 acc[4][4];
    #pragma unroll
    for (int i = 0; i < 4; ++i)
        #pragma unroll
        for (int j = 0; j < 4; ++j) acc[i][j] = fzero;

    const int frag_off = ((lane >> 4) << 8) + ((lane & 15) << 4);  // = lane*16
    const int ag = (wave >> 1) * 4;
    const int bg = (wave & 1) * 4;
    const int wq = wave << 13;            // this wave's 8KB quarter offset

    auto stage = [&](int buf, int kt) {
        const unsigned short* src = mysrc + kt * 4096;
        #pragma unroll
        for (int c = 0; c < 8; ++c) {
            __builtin_amdgcn_global_load_lds(
                (gptr_t)(uintptr_t)(src + (c << 9) + (lane << 3)),
                (lptr_t)(uintptr_t)(&lds[(buf << 15) + wq + (c << 10)]),
                16, 0, 0);
        }
    };

    stage(0, 0);
    __syncthreads();                      // buf0 resident

    int cur = 0;
    for (int kt = 0; kt < 32; ++kt) {
        if (kt + 1 < 32) stage(cur ^ 1, kt + 1);   // issue early: hides latency

        const unsigned char* base = &lds[cur << 15];
        short8 ah[4], al[4], bh[4], bl[4];
        #pragma unroll
        for (int i = 0; i < 4; ++i) {
            const int ao = (ag + i) * 1024 + frag_off;
            const int bo = (bg + i) * 1024 + frag_off;
            ah[i] = __builtin_bit_cast(short8, *(const uint4*)&base[ao]);
            al[i] = __builtin_bit_cast(short8, *(const uint4*)&base[8192 + ao]);
            bh[i] = __builtin_bit_cast(short8, *(const uint4*)&base[16384 + bo]);
            bl[i] = __builtin_bit_cast(short8, *(const uint4*)&base[24576 + bo]);
        }
        #pragma unroll
        for (int i = 0; i < 4; ++i)
            #pragma unroll
            for (int j = 0; j < 4; ++j) {
                acc[i][j] = __builtin_amdgcn_mfma_f32_16x16x32_bf16(ah[i], bh[j], acc[i][j], 0, 0, 0);
                acc[i][j] = __builtin_amdgcn_mfma_f32_16x16x32_bf16(ah[i], bl[j], acc[i][j], 0, 0, 0);
                acc[i][j] = __builtin_amdgcn_mfma_f32_16x16x32_bf16(al[i], bh[j], acc[i][j], 0, 0, 0);
            }

        __syncthreads();   // implicit vmcnt(0): next tile resident; reads done
        cur ^= 1;
    }

    // epilogue: C/D layout col=lane&15, row=(lane>>4)*4+reg
    const int gm_base = bm * 128 + (wave >> 1) * 64 + ((lane >> 4) << 2);
    const int gn_base = bn * 128 + (wave & 1) * 64 + (lane & 15);
    #pragma unroll
    for (int j = 0; j < 4; ++j) {
        const int gn = gn_base + j * 16;
        const float bj = bias[gn];
        if (EPI == 0) {
            #pragma unroll
            for (int i = 0; i < 4; ++i)
                #pragma unroll
                for (int r = 0; r < 4; ++r)
                    o0[(size_t)(gm_base + i * 16 + r) * NXDIM + gn] = acc[i][j][r] + bj;
        } else {
            const int sec = gn >> 10;
            const int hh  = (gn >> 6) & 15;
            const int d   = gn & 63;
            #pragma unroll
            for (int i = 0; i < 4; ++i)
                #pragma unroll
                for (int r = 0; r < 4; ++r) {
                    const int gm = gm_base + i * 16 + r;
                    const int bq = gm >> 10, s = gm & 1023;
                    const size_t idx = (((size_t)bq * NHEAD + hh) * SEQ + s) * DHEAD + d;
                    const float val = acc[i][j][r] + bj;
                    if (sec == 1)      o1[idx] = val;
                    else if (sec == 2) o2[idx] = val;
                    else {
                        // fold 1/sqrt(D) * log2(e): exp2-domain logits
                        const float vq = val * 0.18033688f;
                        const unsigned short hq = f2bf(vq);
                        qh_o[idx] = hq;
                        ql_o[idx] = f2bf(vq - bf2f(hq));
                    }
                }
        }
    }
}

// ---------------------------------------------------------------------------
// MFMA flash attention, causal-balanced: block handles q-tile pair
// (pp, 15-pp) sequentially -> uniform 17 k-tiles/block, grid 512.
// exp2-domain softmax (log2e folded into Q), lsum via ones-MFMA,
// defer-max rescale (THR=8), setprio around MFMA clusters.
// ---------------------------------------------------------------------------
__global__ __launch_bounds__(256, 3) void attn_kernel(
    const unsigned short* __restrict__ qh_g, const unsigned short* __restrict__ ql_g,
    const float* __restrict__ kbuf, const float* __restrict__ vbuf,
    unsigned short* __restrict__ ahi, unsigned short* __restrict__ alo)
{
    __shared__ unsigned char lds[49152];
    unsigned char* const Kh  = lds;              // [key][d] hi, swizzled slots
    unsigned char* const Kl  = lds + 8192;
    unsigned char* const Vth = lds + 16384;      // [d][key] hi (transposed)
    unsigned char* const Vtl = lds + 24576;

    const int tid  = threadIdx.x;
    const int wave = tid >> 6, lane = tid & 63;
    const int l15  = lane & 15, lg = lane >> 4;
    const int pp = (int)(blockIdx.x & 7);        // pair index
    const int bh = (int)(blockIdx.x >> 3);
    unsigned char* const Ps = lds + 32768 + (wave << 12);  // per-wave 4KB

    const float* kb = kbuf + (size_t)bh * SEQ * DHEAD;
    const float* vb = vbuf + (size_t)bh * SEQ * DHEAD;

    const int krow = tid >> 2, kdq = (tid & 3) << 4;  // K staging: row, d-base
    const int vrow = tid & 63, vkq = tid >> 6;        // V staging: Vt row(=d), key-quarter

    float4 kreg[4];
    float  vreg[16];

    auto load_tile = [&](int kb0) {
        #pragma unroll
        for (int c = 0; c < 4; ++c)
            kreg[c] = *(const float4*)&kb[(size_t)(kb0 + krow) * DHEAD + kdq + 4 * c];
        #pragma unroll
        for (int kk = 0; kk < 16; ++kk)
            vreg[kk] = vb[(size_t)(kb0 + vkq * 16 + kk) * DHEAD + vrow];
    };
    auto commit = [&]() {
        #pragma unroll
        for (int c = 0; c < 4; ++c) {
            const float4 f = kreg[c];
            const unsigned h01 = pk_hi_rtne(f.x, f.y);
            const unsigned h23 = pk_hi_rtne(f.z, f.w);
            const unsigned l01 = pk_hi_trunc(f.x - rtne_bf(f.x), f.y - rtne_bf(f.y));
            const unsigned l23 = pk_hi_trunc(f.z - rtne_bf(f.z), f.w - rtne_bf(f.w));
            const int slot = ((tid & 3) << 1) + (c >> 1);
            const int addr = krow * 128 + ((slot ^ (krow & 7)) << 4) + ((c & 1) << 3);
            *(uint2*)(Kh + addr) = make_uint2(h01, h23);
            *(uint2*)(Kl + addr) = make_uint2(l01, l23);
        }
        unsigned vhp[8], vlp[8];
        #pragma unroll
        for (int p = 0; p < 8; ++p) {
            const float a = vreg[2 * p], b2 = vreg[2 * p + 1];
            vhp[p] = pk_hi_trunc(a, b2);
            vlp[p] = pk_hi_trunc(a - trunc_bf(a), b2 - trunc_bf(b2));
        }
        const int vs0 = vkq << 1;
        const int vb0 = vrow * 128;
        const int vsw = vrow & 7;
        *(uint4*)(Vth + vb0 + (((vs0    ) ^ vsw) << 4)) = make_uint4(vhp[0], vhp[1], vhp[2], vhp[3]);
        *(uint4*)(Vth + vb0 + (((vs0 + 1) ^ vsw) << 4)) = make_uint4(vhp[4], vhp[5], vhp[6], vhp[7]);
        *(uint4*)(Vtl + vb0 + (((vs0    ) ^ vsw) << 4)) = make_uint4(vlp[0], vlp[1], vlp[2], vlp[3]);
        *(uint4*)(Vtl + vb0 + (((vs0 + 1) ^ vsw) << 4)) = make_uint4(vlp[4], vlp[5], vlp[6], vlp[7]);
    };

    const int fsw = lg ^ (l15 & 7);   // frag slot swizzle (ks=0)
    const int hh = bh & 15, bq = bh >> 4;

    short8 vone;
    #pragma unroll
    for (int e = 0; e < 8; ++e) vone[e] = (short)0x3F80;   // bf16 1.0

    auto process = [&](int q0, int nt, bool has_next) {
        // Q A-fragments in registers: row=l15, k=lg*8+e (pre-scaled, exp2 dom)
        short8 qhf[2], qlf[2];
        {
            const size_t qb0 = ((size_t)bh * SEQ + q0 + wave * 16 + l15) * DHEAD + lg * 8;
            qhf[0] = *(const short8*)(qh_g + qb0);
            qhf[1] = *(const short8*)(qh_g + qb0 + 32);
            qlf[0] = *(const short8*)(ql_g + qb0);
            qlf[1] = *(const short8*)(ql_g + qb0 + 32);
        }
        float mprev[4];
        f32x4 lacc = (f32x4){0.f, 0.f, 0.f, 0.f};
        f32x4 oacc[4];
        #pragma unroll
        for (int r = 0; r < 4; ++r) mprev[r] = -3.0e38f;
        #pragma unroll
        for (int jd = 0; jd < 4; ++jd) oacc[jd] = (f32x4){0.f, 0.f, 0.f, 0.f};

        for (int kt = 0; kt < nt; ++kt) {
            __syncthreads();              // staged K/V visible
            const bool pf = (kt + 1 < nt) || has_next;
            if (pf) load_tile((kt + 1 < nt) ? (kt + 1) << 6 : 0);

            // ---- scores: S = Q·K^T (3-term split)
            f32x4 sacc[4];
            #pragma unroll
            for (int j = 0; j < 4; ++j) sacc[j] = (f32x4){0.f, 0.f, 0.f, 0.f};
            __builtin_amdgcn_s_setprio(1);
            #pragma unroll
            for (int ks = 0; ks < 2; ++ks) {
                #pragma unroll
                for (int j = 0; j < 4; ++j) {
                    const int addr = ((j << 4) + l15) * 128 + ((fsw ^ (ks << 2)) << 4);
                    const short8 khf = *(const short8*)(Kh + addr);
                    const short8 klf = *(const short8*)(Kl + addr);
                    sacc[j] = __builtin_amdgcn_mfma_f32_16x16x32_bf16(qhf[ks], khf, sacc[j], 0, 0, 0);
                    sacc[j] = __builtin_amdgcn_mfma_f32_16x16x32_bf16(qhf[ks], klf, sacc[j], 0, 0, 0);
                    sacc[j] = __builtin_amdgcn_mfma_f32_16x16x32_bf16(qlf[ks], khf, sacc[j], 0, 0, 0);
                }
            }
            __builtin_amdgcn_s_setprio(0);

            // ---- masked row-max (rows owned lane-locally: lg*4+r)
            const int k0 = kt << 6;
            const bool diag = (k0 == q0);
            float mx[4];
            #pragma unroll
            for (int r = 0; r < 4; ++r) {
                const int qg = q0 + wave * 16 + lg * 4 + r;
                float m_ = -3.0e38f;
                #pragma unroll
                for (int j = 0; j < 4; ++j) {
                    float sv = sacc[j][r];
                    if (diag && (k0 + (j << 4) + l15) > qg) sv = -1.0e9f;
                    sacc[j][r] = sv;
                    m_ = fmaxf(m_, sv);
                }
                m_ = fmaxf(m_, __shfl_xor(m_, 1));
                m_ = fmaxf(m_, __shfl_xor(m_, 2));
                m_ = fmaxf(m_, __shfl_xor(m_, 4));
                m_ = fmaxf(m_, __shfl_xor(m_, 8));
                mx[r] = m_;
            }

            // ---- defer-max: rescale only when some row grew past THR=8
            bool need = false;
            #pragma unroll
            for (int r = 0; r < 4; ++r) need |= (mx[r] > mprev[r] + 8.0f);
            if (__any(need)) {
                #pragma unroll
                for (int r = 0; r < 4; ++r) {
                    const float mnew = fmaxf(mprev[r], mx[r]);
                    const float corr = exp2f(mprev[r] - mnew);
                    lacc[r] *= corr;
                    #pragma unroll
                    for (int jd = 0; jd < 4; ++jd) oacc[jd][r] *= corr;
                    mprev[r] = mnew;
                }
            }

            // ---- P = exp2(S - m), packed (hi16|lo16) -> per-wave LDS
            #pragma unroll
            for (int j = 0; j < 4; ++j)
                #pragma unroll
                for (int r = 0; r < 4; ++r) {
                    const float p = exp2f(sacc[j][r] - mprev[r]);
                    const unsigned up = __float_as_uint(p);
                    const float plo = p - __uint_as_float(up & 0xFFFF0000u);
                    const unsigned packed = (up & 0xFFFF0000u) | (__float_as_uint(plo) >> 16);
                    const int qq = lg * 4 + r;
                    const int kcol = (j << 4) + l15;
                    const int addr = qq * 256 + (((kcol >> 2) ^ qq) << 4) + ((kcol & 3) << 2);
                    *(unsigned*)(Ps + addr) = packed;
                }

            // ---- PV: O += P·V (3-term split); lsum via ones-MFMA
            __builtin_amdgcn_s_setprio(1);
            #pragma unroll
            for (int ks = 0; ks < 2; ++ks) {
                const int s0 = (ks << 3) + (lg << 1);
                const uint4 pk0 = *(const uint4*)(Ps + l15 * 256 + (((s0    ) ^ l15) << 4));
                const uint4 pk1 = *(const uint4*)(Ps + l15 * 256 + (((s0 + 1) ^ l15) << 4));
                uint4 uh, ul;
                uh.x = __builtin_amdgcn_perm(pk0.y, pk0.x, 0x07060302u);
                uh.y = __builtin_amdgcn_perm(pk0.w, pk0.z, 0x07060302u);
                uh.z = __builtin_amdgcn_perm(pk1.y, pk1.x, 0x07060302u);
                uh.w = __builtin_amdgcn_perm(pk1.w, pk1.z, 0x07060302u);
                ul.x = __builtin_amdgcn_perm(pk0.y, pk0.x, 0x05040100u);
                ul.y = __builtin_amdgcn_perm(pk0.w, pk0.z, 0x05040100u);
                ul.z = __builtin_amdgcn_perm(pk1.y, pk1.x, 0x05040100u);
                ul.w = __builtin_amdgcn_perm(pk1.w, pk1.z, 0x05040100u);
                const short8 phf = __builtin_bit_cast(short8, uh);
                const short8 plf = __builtin_bit_cast(short8, ul);
                lacc = __builtin_amdgcn_mfma_f32_16x16x32_bf16(phf, vone, lacc, 0, 0, 0);
                lacc = __builtin_amdgcn_mfma_f32_16x16x32_bf16(plf, vone, lacc, 0, 0, 0);
                #pragma unroll
                for (int jd = 0; jd < 4; ++jd) {
                    const int vaddr = ((jd << 4) + l15) * 128 + ((fsw ^ (ks << 2)) << 4);
                    const short8 vhf = *(const short8*)(Vth + vaddr);
                    const short8 vlf = *(const short8*)(Vtl + vaddr);
                    oacc[jd] = __builtin_amdgcn_mfma_f32_16x16x32_bf16(phf, vhf, oacc[jd], 0, 0, 0);
                    oacc[jd] = __builtin_amdgcn_mfma_f32_16x16x32_bf16(phf, vlf, oacc[jd], 0, 0, 0);
                    oacc[jd] = __builtin_amdgcn_mfma_f32_16x16x32_bf16(plf, vhf, oacc[jd], 0, 0, 0);
                }
            }
            __builtin_amdgcn_s_setprio(0);

            __syncthreads();              // all LDS reads done
            if (pf) commit();             // write next tile (or pass-B tile 0)
        }

        // ---- epilogue: normalize, split hi/lo, write proj-A tiled layout
        float inv[4];
        #pragma unroll
        for (int r = 0; r < 4; ++r) inv[r] = 1.0f / lacc[r];
        #pragma unroll
        for (int jd = 0; jd < 4; ++jd) {
            const int kcol = (hh << 6) + (jd << 4) + l15;
            const int ktile = kcol >> 5, khalf = (kcol & 31) >> 3, k7 = kcol & 7;
            #pragma unroll
            for (int r = 0; r < 4; ++r) {
                const int m = (bq << 10) + q0 + wave * 16 + lg * 4 + r;
                const float o = oacc[jd][r] * inv[r];
                const unsigned short hv = f2bf(o);
                const unsigned short lv = f2bf(o - bf2f(hv));
                const size_t off = ((size_t)((m >> 7) * 32 + ktile) << 12)
                                 + (size_t)((((m & 127) >> 4) << 9) + (khalf << 7) + ((m & 15) << 3) + k7);
                ahi[off] = hv;
                alo[off] = lv;
            }
        }
    };

    load_tile(0);
    commit();
    process(pp << 6, pp + 1, true);              // small pass: tiles 0..pp
    process((15 - pp) << 6, 16 - pp, false);     // big pass:   tiles 0..15-pp
}

extern "C" void kernel_launch(void* const* d_in, const int* in_sizes, int n_in,
                              void* d_out, int out_size, void* d_ws, size_t ws_size,
                              hipStream_t stream) {
    const float* x      = (const float*)d_in[0];
    // d_in[1] = causal mask — analytic, ignored
    const float* w_attn = (const float*)d_in[2];
    const float* b_attn = (const float*)d_in[3];
    const float* w_proj = (const float*)d_in[4];
    const float* b_proj = (const float*)d_in[5];

    float* out = (float*)d_out;
    float* kbuf = out + (size_t)BATCH * SEQ * NXDIM;            // present: k
    float* vbuf = kbuf + (size_t)BATCH * NHEAD * SEQ * DHEAD;   // present: v
    // q hi/lo live in the `a` region of d_out (16MB, dead until proj writes it)
    unsigned short* qh = (unsigned short*)out;                  // 8 MB
    unsigned short* ql = qh + (size_t)BATCH * NHEAD * SEQ * DHEAD;  // 8 MB

    unsigned char* ws = (unsigned char*)d_ws;                   // 32 MB used
    unsigned short* xh  = (unsigned short*)(ws);                // 8 MB
    unsigned short* xl  = (unsigned short*)(ws + (8u  << 20));  // 8 MB
    unsigned short* wah = (unsigned short*)(ws + (16u << 20));  // 6 MB
    unsigned short* wal = (unsigned short*)(ws + (22u << 20));  // 6 MB
    unsigned short* wph = (unsigned short*)(ws + (28u << 20));  // 2 MB
    unsigned short* wpl = (unsigned short*)(ws + (30u << 20));  // 2 MB
    unsigned short* ah  = xh;   // x-split dead after qkv gemm — reuse
    unsigned short* al  = xl;

    split_all_kernel<<<4096, 256, 0, stream>>>(
        x, w_attn, w_proj, xh, xl, wah, wal, wph, wpl);
    mfma_gemm_kernel<1><<<dim3(24, 32), 256, 0, stream>>>(
        xh, xl, wah, wal, b_attn, nullptr, kbuf, vbuf, qh, ql);
    attn_kernel<<<512, 256, 0, stream>>>(qh, ql, kbuf, vbuf, ah, al);
    mfma_gemm_kernel<0><<<dim3(8, 32), 256, 0, stream>>>(
        ah, al, wph, wpl, b_proj, out, nullptr, nullptr, nullptr, nullptr);
}